// Round 11
// baseline (1219.922 us; speedup 1.0000x reference)
//
#include <hip/hip_runtime.h>
#include <hip/hip_fp16.h>
#include <cstdint>
#include <cstddef>

#define BATCH 8
#define NN 2048
#define RTOT 16384   // BATCH*NN
#define CAP 176      // ELL row capacity
#define NBLK 512     // 2 blocks/CU x 256 CU: all co-resident by LDS construction

// ---------------- workspace layout (offsets in floats) ----------------
// Buckets + barrier counters zeroed by hipMemsetAsync BEFORE the mega-kernel
// (dispatch boundary invalidates L1 -> in-kernel atomics + plain reads are safe).
// ALL other buffers are WRITE-ONCE inside the kernel (no address rewritten) so
// per-CU L1 can never serve stale data across grid barriers.
static constexpr size_t OF_B1W   = 0;         // [30][64][2]
static constexpr size_t OF_B1B   = 3840;
static constexpr size_t OF_B2W   = 7680;
static constexpr size_t OF_B2B   = 11520;
static constexpr size_t OF_B3W   = 15360;     // [30][8][2]
static constexpr size_t OF_B3B   = 15840;     // [100][8][2]
static constexpr size_t OF_S2    = 17440;     // [3][30][2]
static constexpr size_t OF_CNT   = 17620;     // int cnt (grid barriers), int cnt2 (s2 barriers)
static constexpr size_t ZEND     = 17632;
static constexpr size_t OF_ELLV  = 17664;                     // fp32 16384*176
static constexpr size_t OF_ELLC  = OF_ELLV + 2883584;         // u16, 1441792 floats
static constexpr size_t OF_ROWLEN= OF_ELLC + 1441792;
static constexpr size_t OF_DINVW = OF_ROWLEN + 16384;
static constexpr size_t OF_DINVB = OF_DINVW + 16384;
static constexpr size_t OF_HWB1  = OF_DINVB + 16384;          // fp16 [RTOT][64] (build out)
static constexpr size_t OF_HWB2  = OF_HWB1 + 524288;          // fp16 [RTOT][64] (apply1 out)
static constexpr size_t OF_HW3   = OF_HWB2 + 524288;          // fp16 [RTOT][32]
static constexpr size_t OF_HB100 = OF_HW3 + 262144;           // fp16 [RTOT][104]
static constexpr size_t OF_S     = OF_HB100 + 851968;         // fp16 [RTOT][104] (fcpool out)
static constexpr size_t OF_ZWA   = OF_S + 851968;             // fp32 stride 32 (L1)
static constexpr size_t OF_ZBA   = OF_ZWA + 524288;
static constexpr size_t OF_ZWB   = OF_ZBA + 524288;           // (L2)
static constexpr size_t OF_ZBB   = OF_ZWB + 524288;
static constexpr size_t OF_ZWC   = OF_ZBB + 524288;           // (L3 w)
static constexpr size_t OF_ZBC   = OF_ZWC + 524288;           // fp32 stride 104 (L3 b)
static constexpr size_t OF_AS    = OF_ZBC + 1703936;          // fp32 stride 104
static constexpr size_t OF_X11   = OF_AS + 1703936;           // fp32 stride 32
static constexpr size_t OF_X12   = OF_X11 + 524288;
static constexpr size_t OF_X13   = OF_X12 + 524288;
static constexpr size_t OF_S11   = OF_X13 + 524288;
static constexpr size_t OF_S12   = OF_S11 + 524288;
static constexpr size_t OF_PP    = OF_S12 + 524288;           // 64*13000
static constexpr size_t OF_PARTMAX = OF_PP + 832000;          // 64*90

#define FMA4(acc, s, h) { acc.x += (s)*(h).x; acc.y += (s)*(h).y; acc.z += (s)*(h).z; acc.w += (s)*(h).w; }

__device__ __forceinline__ unsigned short f2h(float f) {
  _Float16 h = (_Float16)f;
  return *(unsigned short*)&h;
}
__device__ __forceinline__ float h2f(unsigned short s) {
  _Float16 h = *(_Float16*)&s;
  return (float)h;
}
__device__ __forceinline__ float2 h2f2(unsigned int u) {
  __half2 h = *(__half2*)&u;
  return __half22float2(h);
}

struct __align__(8) us4 { unsigned short x, y, z, w; };

#define ACC8(g, wt) { \
  float2 f0=h2f2((g).x), f1=h2f2((g).y), f2=h2f2((g).z), f3=h2f2((g).w); \
  acc[0] += (wt)*f0.x; acc[1] += (wt)*f0.y; acc[2] += (wt)*f1.x; acc[3] += (wt)*f1.y; \
  acc[4] += (wt)*f2.x; acc[5] += (wt)*f2.y; acc[6] += (wt)*f3.x; acc[7] += (wt)*f3.y; }

// grid barrier: all NBLK blocks co-resident (2/CU by LDS), monotonic counter
__device__ __forceinline__ void gridbar(int* cnt, int target) {
  __syncthreads();
  if (threadIdx.x == 0) {
    __threadfence();
    atomicAdd(cnt, 1);
    while (atomicAdd(cnt, 0) < target) {}
    __threadfence();
  }
  __syncthreads();
}

// ---- spmm pair body (levels 1,2): fp16 interleaved [row][64], 8 lanes/row ----
__device__ __forceinline__ void spmm_pair_body(
    int vb, int t, float* shm,
    const unsigned short* Hwb, const float* ellv, const unsigned short* ellc,
    const int* rowlen, const float* dinvw, const float* dinvb,
    float* Zw, float* Zb, float* bktW, float* bktB)
{
  float* zsW = shm;          // [32][32]
  float* zsB = shm + 1024;   // [32][32]
  int gid = vb * 256 + t;
  int row = gid >> 3, q = gid & 7;
  int side = q >> 2, sub = q & 3;
  int len = rowlen[row];
  const float4* ev = (const float4*)(ellv + (size_t)row * CAP);
  const uint2*  ec = (const uint2*) (ellc + (size_t)row * CAP);
  const uint4* HP = (const uint4*)(Hwb + (size_t)(row >> 11) * (NN*64));
  float acc[8] = {0,0,0,0,0,0,0,0};
  int nit = len >> 2;
  for (int i = 0; i < nit; ++i) {
    float4 v = ev[i];
    uint2 cc = ec[i];
    int c0 = cc.x & 0xffff, c1 = cc.x >> 16, c2 = cc.y & 0xffff, c3 = cc.y >> 16;
    uint4 g0 = HP[c0*8+q], g1 = HP[c1*8+q], g2 = HP[c2*8+q], g3 = HP[c3*8+q];
    float w0 = side ? (v.x>0.f?1.f:0.f) : v.x;
    float w1 = side ? (v.y>0.f?1.f:0.f) : v.y;
    float w2 = side ? (v.z>0.f?1.f:0.f) : v.z;
    float w3 = side ? (v.w>0.f?1.f:0.f) : v.w;
    ACC8(g0, w0); ACC8(g1, w1); ACC8(g2, w2); ACC8(g3, w3);
  }
  uint4 hs = HP[(row & (NN-1))*8 + q];
  ACC8(hs, 1.f);
  float d = side ? dinvb[row] : dinvw[row];
#pragma unroll
  for (int k = 0; k < 8; ++k) acc[k] *= d;
  float* Zp = (side ? Zb : Zw) + (size_t)row*32 + sub*8;
  float4 o0 = {acc[0],acc[1],acc[2],acc[3]}, o1 = {acc[4],acc[5],acc[6],acc[7]};
  ((float4*)Zp)[0] = o0; ((float4*)Zp)[1] = o1;
  int rowloc = t >> 3;
  float* zs = side ? zsB : zsW;
#pragma unroll
  for (int k = 0; k < 8; ++k) zs[rowloc*32 + sub*8+k] = acc[k];
  __syncthreads();
  int copy = vb & 63;
  if (t < 30) {
    float s1 = 0.f, s2 = 0.f;
    for (int r = 0; r < 32; ++r) { float v = zsW[r*32 + t]; s1 += v; s2 += v*v; }
    atomicAdd(&bktW[(t*64+copy)*2],   s1);
    atomicAdd(&bktW[(t*64+copy)*2+1], s2);
  } else if (t >= 64 && t < 94) {
    int c = t - 64;
    float s1 = 0.f, s2 = 0.f;
    for (int r = 0; r < 32; ++r) { float v = zsB[r*32 + c]; s1 += v; s2 += v*v; }
    atomicAdd(&bktB[(c*64+copy)*2],   s1);
    atomicAdd(&bktB[(c*64+copy)*2+1], s2);
  }
}

// ---- apply phase (stage once, loop vbs): BN inline-reduce -> x/s store -> W GEMM -> fp16 ----
template<int LEVEL>
__device__ __forceinline__ void apply_phase(
    int blk, int t, float* shm,
    const float* Zw, const float* bktW, const float* gW, const float* beW,
    float* xst, const float* Ww, const float* dinvw,
    const float* Zb, const float* bktB, const float* gB, const float* beB,
    float* sst, const float* Wb, const float* dinvb,
    unsigned short* HwOut, unsigned short* HbOut)
{
  constexpr int NGB = (LEVEL == 1) ? 8 : 26;
  constexpr int OSTRIDEB = (LEVEL == 1) ? 32 : 104;
  constexpr int NG = 8 + NGB;
  constexpr int NVB = RTOT * NG / 256;
  float* WwL = shm;           // 960
  float* WbL = shm + 960;     // up to 3120
  float* awL = shm + 4080;
  float* abL = shm + 4140;
  if (t < 60) {
    int c = t % 30;
    bool isW = t < 30;
    const float4* p = (const float4*)((isW ? bktW : bktB) + c*128);
    float s1 = 0.f, s2 = 0.f;
#pragma unroll
    for (int k = 0; k < 32; ++k) { float4 v = p[k]; s1 += v.x + v.z; s2 += v.y + v.w; }
    float mean = s1/16384.f, var = s2/16384.f - mean*mean, inv = rsqrtf(var + 1e-5f);
    float aa = (isW ? gW : gB)[c]*inv;
    float* dst = isW ? awL : abL;
    dst[c] = aa; dst[30+c] = (isW ? beW : beB)[c] - mean*aa;
  }
  for (int idx = t; idx < 30*32; idx += 256) {
    int k = idx >> 5, c = idx & 31;
    WwL[idx] = (c < 30) ? Ww[k*30 + c] : 0.f;
  }
  if (LEVEL == 1) {
    for (int idx = t; idx < 30*32; idx += 256) {
      int k = idx >> 5, c = idx & 31;
      WbL[idx] = (c < 30) ? Wb[k*30 + c] : 0.f;
    }
  } else {
    for (int idx = t; idx < 30*OSTRIDEB; idx += 256) {
      int k = idx / OSTRIDEB, j = idx % OSTRIDEB;
      WbL[idx] = (j < 100) ? Wb[k*100 + j] : 0.f;
    }
  }
  __syncthreads();
  for (int vb = blk; vb < NVB; vb += NBLK) {
    int gid = vb * 256 + t;
    int row = gid / NG, g = gid % NG;
    if (g < 8) {
      const float4* Z4 = (const float4*)Zw + (size_t)row*8;
      float4 z4[8];
#pragma unroll
      for (int u = 0; u < 8; ++u) z4[u] = Z4[u];
      const float* z = (const float*)z4;
      float4 xv;
      int ch = 4*g;
      xv.x = (ch+0 < 30) ? awL[ch+0]*z[ch+0] + awL[30+ch+0] : 0.f;
      xv.y = (ch+1 < 30) ? awL[ch+1]*z[ch+1] + awL[30+ch+1] : 0.f;
      xv.z = (ch+2 < 30) ? awL[ch+2]*z[ch+2] + awL[30+ch+2] : 0.f;
      xv.w = (ch+3 < 30) ? awL[ch+3]*z[ch+3] + awL[30+ch+3] : 0.f;
      ((float4*)xst)[(size_t)row*8+g] = xv;
      float4 o = {0,0,0,0};
#pragma unroll
      for (int k = 0; k < 30; ++k) {
        float xk = awL[k]*z[k] + awL[30+k];
        float4 w = *(const float4*)(WwL + k*32 + 4*g);
        FMA4(o, xk, w);
      }
      float d = dinvw[row];
      us4 pv = { f2h(d*o.x), f2h(d*o.y), f2h(d*o.z), f2h(d*o.w) };
      unsigned short* dst = (LEVEL == 1) ? (HwOut + (size_t)row*64 + 4*g)
                                         : (HwOut + (size_t)row*32 + 4*g);
      *(us4*)dst = pv;
    } else {
      int gb = g - 8;
      const float4* Z4 = (const float4*)Zb + (size_t)row*8;
      float4 z4[8];
#pragma unroll
      for (int u = 0; u < 8; ++u) z4[u] = Z4[u];
      const float* z = (const float*)z4;
      if (gb < 8) {
        int ch = 4*gb;
        float4 sv;
        sv.x = (ch+0 < 30) ? abL[ch+0]*z[ch+0] + abL[30+ch+0] : 0.f;
        sv.y = (ch+1 < 30) ? abL[ch+1]*z[ch+1] + abL[30+ch+1] : 0.f;
        sv.z = (ch+2 < 30) ? abL[ch+2]*z[ch+2] + abL[30+ch+2] : 0.f;
        sv.w = (ch+3 < 30) ? abL[ch+3]*z[ch+3] + abL[30+ch+3] : 0.f;
        ((float4*)sst)[(size_t)row*8+gb] = sv;
      }
      float4 o = {0,0,0,0};
#pragma unroll
      for (int k = 0; k < 30; ++k) {
        float sk = abL[k]*z[k] + abL[30+k];
        float4 w = *(const float4*)(WbL + k*OSTRIDEB + 4*gb);
        FMA4(o, sk, w);
      }
      float d = dinvb[row];
      us4 pv = { f2h(d*o.x), f2h(d*o.y), f2h(d*o.z), f2h(d*o.w) };
      unsigned short* dst = (LEVEL == 1) ? (HbOut + (size_t)row*64 + 32 + 4*gb)
                                         : (HbOut + (size_t)row*104 + 4*gb);
      *(us4*)dst = pv;
    }
  }
}

// =================== THE MEGA-KERNEL ===================
__global__ __launch_bounds__(256) void k_mega(
    const float* adj, const float* x, const float* Win, const float* W3030,
    const float* Wp13, const float* Wfc, const float* bfc,
    const float* W1, const float* b1, const float* W2, const float* b2,
    const float* g30, const float* be30, const float* g100, const float* be100,
    float* wsf, float* out)
{
  __shared__ float shm[17664];   // 70.7 KB -> exactly 2 blocks/CU -> 512 co-resident
  const int blk = blockIdx.x, t = threadIdx.x;
  int* cnt  = (int*)(wsf + OF_CNT);
  int* cnt2 = cnt + 1;
  float* ellv = wsf + OF_ELLV;
  unsigned short* ellc = (unsigned short*)(wsf + OF_ELLC);
  int* rowlen = (int*)(wsf + OF_ROWLEN);
  float* dinvw = wsf + OF_DINVW;
  float* dinvb = wsf + OF_DINVB;
  unsigned short* Hwb1 = (unsigned short*)(wsf + OF_HWB1);
  unsigned short* Hwb2 = (unsigned short*)(wsf + OF_HWB2);
  unsigned short* Hw3  = (unsigned short*)(wsf + OF_HW3);
  unsigned short* Hb100= (unsigned short*)(wsf + OF_HB100);
  unsigned short* S    = (unsigned short*)(wsf + OF_S);
  float* ZwA = wsf + OF_ZWA;  float* ZbA = wsf + OF_ZBA;
  float* ZwB = wsf + OF_ZWB;  float* ZbB = wsf + OF_ZBB;
  float* ZwC = wsf + OF_ZWC;  float* ZbC = wsf + OF_ZBC;
  float* As  = wsf + OF_AS;
  float* x11 = wsf + OF_X11;  float* x12 = wsf + OF_X12;  float* x13 = wsf + OF_X13;
  float* s11 = wsf + OF_S11;  float* s12 = wsf + OF_S12;
  float* pp  = wsf + OF_PP;   float* partmax = wsf + OF_PARTMAX;
  float* bL1W = wsf + OF_B1W;  float* bL1B = wsf + OF_B1B;
  float* bL2W = wsf + OF_B2W;  float* bL2B = wsf + OF_B2B;
  float* bL3W = wsf + OF_B3W;  float* bL3B = wsf + OF_B3B;
  float* bktS2 = wsf + OF_S2;

  // ---- P0: build ELL + degrees + H1 (32 rows/block) ----
  {
    int* wcnt = (int*)shm;
    float* wsumA = shm + 4;
    float* dsh = shm + 8;
    int lane = t & 63, wv = t >> 6;
    for (int r = blk; r < RTOT; r += NBLK) {
      __syncthreads();
      const float* row = adj + (size_t)r * NN;
      float4 a = ((const float4*)row)[t];
      float4 b = ((const float4*)row)[256 + t];
      float vals[8] = {a.x, a.y, a.z, a.w, b.x, b.y, b.z, b.w};
      int cbase0 = t*4, cbase1 = 1024 + t*4;
      int cnt_ = 0; float sum = 0.f;
#pragma unroll
      for (int k = 0; k < 8; ++k) { sum += vals[k]; cnt_ += (vals[k] != 0.f) ? 1 : 0; }
      int pre = cnt_;
#pragma unroll
      for (int o = 1; o < 64; o <<= 1) { int n = __shfl_up(pre, o); if (lane >= o) pre += n; }
      int excl = pre - cnt_;
      int wtot = __shfl(pre, 63);
#pragma unroll
      for (int o = 32; o; o >>= 1) sum += __shfl_down(sum, o);
      if (lane == 0) { wcnt[wv] = wtot; wsumA[wv] = sum; }
      __syncthreads();
      int base = 0;
      for (int w = 0; w < wv; ++w) base += wcnt[w];
      int p = base + excl;
      size_t rb = (size_t)r * CAP;
#pragma unroll
      for (int k = 0; k < 8; ++k) {
        float v = vals[k];
        if (v != 0.f && p < CAP) {
          ellv[rb + p] = v;
          ellc[rb + p] = (unsigned short)((k < 4) ? (cbase0 + k) : (cbase1 + (k - 4)));
          ++p;
        }
      }
      if (t == 0) {
        int tot = wcnt[0] + wcnt[1] + wcnt[2] + wcnt[3];
        float ws = wsumA[0] + wsumA[1] + wsumA[2] + wsumA[3];
        int nnz = tot < CAP ? tot : CAP;
        int n = nnz;
        while ((n & 3) && n < CAP) { ellv[rb + n] = 0.f; ellc[rb + n] = 0; ++n; }
        rowlen[r] = n;
        float dw = rsqrtf(ws + 1.f), db = rsqrtf((float)nnz + 1.f);
        dinvw[r] = dw; dinvb[r] = db;
        dsh[0] = dw; dsh[1] = db;
      }
      __syncthreads();
      if (t < 64) {
        int c = t & 31, side = t >> 5;
        float v = 0.f;
        if (c < 30) {
          float x0 = x[r*3], x1 = x[r*3+1], x2 = x[r*3+2];
          const float* W = Win + side*90;
          v = (x0*W[c] + x1*W[30+c] + x2*W[60+c]) * dsh[side];
        }
        Hwb1[(size_t)r*64 + t] = f2h(v);
      }
    }
  }
  gridbar(cnt, 1*NBLK);

  // ---- P1: SpMM pair L1 ----
  spmm_pair_body(blk, t, shm, Hwb1, ellv, ellc, rowlen, dinvw, dinvb, ZwA, ZbA, bL1W, bL1B);
  gridbar(cnt, 2*NBLK);

  // ---- P2: apply L1 -> x11, s11, Hwb2 ----
  apply_phase<1>(blk, t, shm, ZwA, bL1W, g30+0, be30+0, x11, W3030+0, dinvw,
                 ZbA, bL1B, g30+90, be30+90, s11, W3030+2*900, dinvb, Hwb2, Hwb2);
  gridbar(cnt, 3*NBLK);

  // ---- P3: SpMM pair L2 ----
  spmm_pair_body(blk, t, shm, Hwb2, ellv, ellc, rowlen, dinvw, dinvb, ZwB, ZbB, bL2W, bL2B);
  gridbar(cnt, 4*NBLK);

  // ---- P4: apply L2 -> x12, s12, Hw3, Hb100 ----
  apply_phase<2>(blk, t, shm, ZwB, bL2W, g30+30, be30+30, x12, W3030+900, dinvw,
                 ZbB, bL2B, g30+120, be30+120, s12, Wp13, dinvb, Hw3, Hb100);
  gridbar(cnt, 5*NBLK);

  // ---- P5: SpMM L3 (w-side vb<256, b-side vb 256..1087) ----
  for (int vb = blk; vb < 1088; vb += NBLK) {
    __syncthreads();
    if (vb < 256) {
      float* zs = shm;            // [64][32]
      int gid = vb * 256 + t;
      int row = gid >> 2, q = gid & 3;
      int len = rowlen[row];
      const float4* ev = (const float4*)(ellv + (size_t)row * CAP);
      const uint2*  ec = (const uint2*) (ellc + (size_t)row * CAP);
      const uint4* HP = (const uint4*)(Hw3 + (size_t)(row >> 11) * (NN*32));
      float acc[8] = {0,0,0,0,0,0,0,0};
      int nit = len >> 2;
      for (int i = 0; i < nit; ++i) {
        float4 v = ev[i];
        uint2 cc = ec[i];
        int c0 = cc.x & 0xffff, c1 = cc.x >> 16, c2 = cc.y & 0xffff, c3 = cc.y >> 16;
        uint4 g0 = HP[c0*4+q], g1 = HP[c1*4+q], g2 = HP[c2*4+q], g3 = HP[c3*4+q];
        ACC8(g0, v.x); ACC8(g1, v.y); ACC8(g2, v.z); ACC8(g3, v.w);
      }
      uint4 hs = HP[(row & (NN-1))*4 + q];
      ACC8(hs, 1.f);
      float d = dinvw[row];
#pragma unroll
      for (int k = 0; k < 8; ++k) acc[k] *= d;
      float* Zp = ZwC + (size_t)row*32 + q*8;
      float4 o0 = {acc[0],acc[1],acc[2],acc[3]}, o1 = {acc[4],acc[5],acc[6],acc[7]};
      ((float4*)Zp)[0] = o0; ((float4*)Zp)[1] = o1;
      int rowloc = t >> 2;
#pragma unroll
      for (int k = 0; k < 8; ++k) zs[rowloc*32 + q*8+k] = acc[k];
      __syncthreads();
      if (t < 30) {
        float s1 = 0.f, s2 = 0.f;
        for (int r = 0; r < 64; ++r) { float v = zs[r*32 + t]; s1 += v; s2 += v*v; }
        int copy = vb & 7;
        atomicAdd(&bL3W[(t*8+copy)*2],   s1);
        atomicAdd(&bL3W[(t*8+copy)*2+1], s2);
      }
    } else {
      float* st = shm + 2048;     // [200]
      int bid = vb - 256;
      for (int i = t; i < 200; i += 256) st[i] = 0.f;
      __syncthreads();
      int gid = bid * 256 + t;    // RTOT*13
      int row = gid / 13, q = gid - row*13;
      int len = rowlen[row];
      const float4* ev = (const float4*)(ellv + (size_t)row * CAP);
      const uint2*  ec = (const uint2*) (ellc + (size_t)row * CAP);
      const uint4* HP = (const uint4*)(Hb100 + (size_t)(row >> 11) * ((size_t)NN*104));
      float acc[8] = {0,0,0,0,0,0,0,0};
      int nit = len >> 2;
      for (int i = 0; i < nit; ++i) {
        float4 v = ev[i];
        uint2 cc = ec[i];
        int c0 = cc.x & 0xffff, c1 = cc.x >> 16, c2 = cc.y & 0xffff, c3 = cc.y >> 16;
        uint4 g0 = HP[c0*13+q], g1 = HP[c1*13+q], g2 = HP[c2*13+q], g3 = HP[c3*13+q];
        float w0 = (v.x>0.f?1.f:0.f), w1 = (v.y>0.f?1.f:0.f);
        float w2 = (v.z>0.f?1.f:0.f), w3 = (v.w>0.f?1.f:0.f);
        ACC8(g0, w0); ACC8(g1, w1); ACC8(g2, w2); ACC8(g3, w3);
      }
      uint4 hs = HP[(row & (NN-1))*13 + q];
      ACC8(hs, 1.f);
      float d = dinvb[row];
#pragma unroll
      for (int k = 0; k < 8; ++k) acc[k] *= d;
      float* Zp = ZbC + (size_t)row*104 + q*8;
      float4 o0 = {acc[0],acc[1],acc[2],acc[3]}, o1 = {acc[4],acc[5],acc[6],acc[7]};
      ((float4*)Zp)[0] = o0; ((float4*)Zp)[1] = o1;
      int c0 = q*8;
#pragma unroll
      for (int k = 0; k < 8; ++k) {
        int ch = c0 + k;
        if (ch < 100) { atomicAdd(&st[ch*2], acc[k]); atomicAdd(&st[ch*2+1], acc[k]*acc[k]); }
      }
      __syncthreads();
      int copy = bid & 7;
      for (int i = t; i < 200; i += 256)
        atomicAdd(&bL3B[((i>>1)*8 + copy)*2 + (i&1)], st[i]);
    }
  }
  gridbar(cnt, 6*NBLK);

  // ---- P6: fcpool (blk<256): x13, s1 -> softmax -> fp16 S ----
  if (blk < 256) {
    float* feat = shm;            // 64x160 = 10240
    float* Wl = shm + 10240;      // 40x100 = 4000
    float* aw3 = shm + 14240;     // 60
    float* ab3 = shm + 14300;     // 200
    int g0 = blk * 64;
    if (t < 30) {
      const float4* p = (const float4*)(bL3W + t*16);
      float s1 = 0.f, s2 = 0.f;
#pragma unroll
      for (int k = 0; k < 4; ++k) { float4 v = p[k]; s1 += v.x + v.z; s2 += v.y + v.w; }
      float mean = s1/16384.f, var = s2/16384.f - mean*mean, inv = rsqrtf(var + 1e-5f);
      float aa = g30[60+t]*inv; aw3[t] = aa; aw3[30+t] = be30[60+t] - mean*aa;
    } else if (t >= 64 && t < 164) {
      int c = t - 64;
      const float4* p = (const float4*)(bL3B + c*16);
      float s1 = 0.f, s2 = 0.f;
#pragma unroll
      for (int k = 0; k < 4; ++k) { float4 v = p[k]; s1 += v.x + v.z; s2 += v.y + v.w; }
      float mean = s1/16384.f, var = s2/16384.f - mean*mean, inv = rsqrtf(var + 1e-5f);
      float aa = g100[c]*inv; ab3[c] = aa; ab3[100+c] = be100[c] - mean*aa;
    }
    __syncthreads();
    for (int idx = t; idx < 64*160; idx += 256) {
      int l = idx / 160, c = idx % 160;
      int g = g0 + l;
      float v;
      if (c < 30) v = s11[(size_t)g*32 + c];
      else if (c < 60) v = s12[(size_t)g*32 + (c-30)];
      else { int k = c - 60; v = ab3[k]*ZbC[(size_t)g*104 + k] + ab3[100 + k]; }
      feat[l*160 + c] = v;
    }
    for (int idx = t; idx < 64*32; idx += 256) {
      int l = idx >> 5, c = idx & 31;
      int g = g0 + l;
      x13[(size_t)g*32+c] = (c < 30) ? aw3[c]*ZwC[(size_t)g*32+c] + aw3[30+c] : 0.f;
    }
    int np = t >> 3, kg = t & 7;
    int n0 = np*2, n1 = np*2 + 1;
    int kbase = kg*12 + (kg < 4 ? kg : 4);
    int klen  = kg < 4 ? 13 : 12;
    float a0[13], a1[13];
#pragma unroll
    for (int j = 0; j < 13; ++j) { a0[j] = 0.f; a1[j] = 0.f; }
    for (int ch = 0; ch < 4; ++ch) {
      __syncthreads();
      for (int idx = t; idx < 4000; idx += 256) {
        int r = idx/100, j = idx%100;
        Wl[r*100 + j] = Wfc[(ch*40 + r)*100 + j];
      }
      __syncthreads();
      for (int kk = 0; kk < 40; ++kk) {
        float f0 = feat[n0*160 + ch*40+kk];
        float f1 = feat[n1*160 + ch*40+kk];
#pragma unroll
        for (int j = 0; j < 13; ++j) {
          if (j < klen) {
            float w = Wl[kk*100 + kbase + j];
            a0[j] += f0*w; a1[j] += f1*w;
          }
        }
      }
    }
    __syncthreads();
    float* sRow = shm;   // reuse as [64][100]
    for (int j = 0; j < klen; ++j) {
      int k = kbase + j;
      sRow[n0*100 + k] = a0[j] + bfc[k];
      sRow[n1*100 + k] = a1[j] + bfc[k];
    }
    __syncthreads();
    int n = t >> 2, part = t & 3;
    int i0 = part*25;
    float m = -3.4e38f;
    for (int i = 0; i < 25; ++i) m = fmaxf(m, sRow[n*100 + i0 + i]);
    m = fmaxf(m, __shfl_xor(m, 1));
    m = fmaxf(m, __shfl_xor(m, 2));
    float ev[25]; float s = 0.f;
    for (int i = 0; i < 25; ++i) { float e = __expf(sRow[n*100 + i0 + i] - m); ev[i] = e; s += e; }
    s += __shfl_xor(s, 1);
    s += __shfl_xor(s, 2);
    float rinv = 1.f / s;
    for (int i = 0; i < 25; ++i) S[(size_t)(g0+n)*104 + i0 + i] = f2h(ev[i] * rinv);
    if (part == 3) {
      S[(size_t)(g0+n)*104 + 100] = 0; S[(size_t)(g0+n)*104 + 101] = 0;
      S[(size_t)(g0+n)*104 + 102] = 0; S[(size_t)(g0+n)*104 + 103] = 0;
    }
  }
  gridbar(cnt, 7*NBLK);

  // ---- P7: As = adj @ S ----
  for (int vb = blk; vb < 832; vb += NBLK) {
    int gid = vb * 256 + t;
    int row = gid / 13, q = gid - row*13;
    int len = rowlen[row];
    const float4* ev = (const float4*)(ellv + (size_t)row * CAP);
    const uint2*  ec = (const uint2*) (ellc + (size_t)row * CAP);
    const uint4* HP = (const uint4*)(S + (size_t)(row >> 11) * ((size_t)NN*104));
    float acc[8] = {0,0,0,0,0,0,0,0};
    int nit = len >> 2;
    for (int i = 0; i < nit; ++i) {
      float4 v = ev[i];
      uint2 cc = ec[i];
      int c0 = cc.x & 0xffff, c1 = cc.x >> 16, c2 = cc.y & 0xffff, c3 = cc.y >> 16;
      uint4 g0 = HP[c0*13+q], g1 = HP[c1*13+q], g2 = HP[c2*13+q], g3 = HP[c3*13+q];
      ACC8(g0, v.x); ACC8(g1, v.y); ACC8(g2, v.z); ACC8(g3, v.w);
    }
    float* Zp = As + (size_t)row*104 + q*8;
    float4 o0 = {acc[0],acc[1],acc[2],acc[3]}, o1 = {acc[4],acc[5],acc[6],acc[7]};
    ((float4*)Zp)[0] = o0; ((float4*)Zp)[1] = o1;
  }
  gridbar(cnt, 8*NBLK);

  // ---- P8: pooled partials + stage-1 col max (blk<64) ----
  if (blk < 64) {
    float* sL = shm;            // [64][100]
    float* xL = shm + 6400;     // [64][132]
    float* red = shm + 14848;   // [256]
    int b = blk >> 3, chunk = blk & 7;
    int g00 = b * 2048 + chunk * 256;
    int kt = t/10, dt = t%10;
    int k0 = kt*4, d0 = dt*13;
    float acc[4][13];
#pragma unroll
    for (int a = 0; a < 4; ++a)
#pragma unroll
      for (int j = 0; j < 13; ++j) acc[a][j] = 0.f;
    for (int tile = 0; tile < 4; ++tile) {
      int g0 = g00 + tile*64;
      __syncthreads();
      for (int idx = t; idx < 64*100; idx += 256) {
        int l = idx/100, k = idx%100;
        sL[l*100 + k] = h2f(S[(size_t)(g0+l)*104 + k]);
      }
      for (int idx = t; idx < 64*130; idx += 256) {
        int l = idx/130, d = idx%130;
        xL[l*132 + d] = d < 30 ? x13[(size_t)(g0+l)*32 + d] : As[(size_t)(g0+l)*104 + (d-30)];
      }
      __syncthreads();
      if (t < 250) {
        for (int kk = 0; kk < 64; ++kk) {
          float sv[4];
#pragma unroll
          for (int a = 0; a < 4; ++a) sv[a] = sL[kk*100 + k0+a];
#pragma unroll
          for (int j = 0; j < 13; ++j) {
            float xv = xL[kk*132 + d0+j];
#pragma unroll
            for (int a = 0; a < 4; ++a) acc[a][j] += sv[a]*xv;
          }
        }
      }
    }
    if (t < 250) {
      float* dst = pp + (size_t)blk * 13000;
      for (int a = 0; a < 4; ++a)
        for (int j = 0; j < 13; ++j)
          dst[(k0+a)*130 + (d0+j)] = acc[a][j];
    }
    __syncthreads();
    {
      int c = t & 31, rg = t >> 5;
      const float* srcs[3] = {x11, x12, x13};
      for (int a = 0; a < 3; ++a) {
        const float* p = srcs[a] + (size_t)(g00+rg)*32 + c;
        float m = -3.4e38f;
        for (int it = 0; it < 32; ++it) m = fmaxf(m, p[it*256]);
        red[t] = m;
        __syncthreads();
        if (t < 30) {
          float mm = red[t];
          for (int g = 1; g < 8; ++g) mm = fmaxf(mm, red[g*32+t]);
          partmax[(size_t)blk*90 + a*30 + t] = mm;
        }
        __syncthreads();
      }
    }
  }
  gridbar(cnt, 9*NBLK);

  if (blk >= 8) return;

  // ---- P9: stage 2 (register-tiled, fp32 A2 in LDS, 8-block barriers on cnt2) ----
  {
    float* A2f  = shm;            // 10000
    float* buf1 = shm + 10000;    // 3000
    float* buf2 = shm + 13000;    // 3200 (T padded [100][32])
    float* WL   = shm + 16200;    // 960
    float* dl   = shm + 17160;    // 100
    float* st1  = shm + 17260;    // 30
    float* st2  = shm + 17290;    // 30
    float* coef = shm + 17320;    // 60
    float* x1L  = shm + 17380;    // 90
    float* x2L  = shm + 17470;    // 90
    float* hh   = shm + 17560;    // 50
    int b = blk;
    __syncthreads();
    for (int idx = t; idx < 13000; idx += 256) {
      float s = 0.f;
      for (int ch = 0; ch < 8; ++ch) s += pp[(size_t)(b*8 + ch)*13000 + idx];
      int k = idx/130, d = idx%130;
      if (d < 30) buf1[k*30 + d] = s;
      else A2f[k*100 + (d-30)] = s;
    }
    __syncthreads();
    if (t < 100 && A2f[t*101] == 0.f) A2f[t*101] = 1.f;
    __syncthreads();
    if (t < 100) {
      float s = 0.f;
      for (int j = 0; j < 100; ++j) s += A2f[t*100 + j];
      dl[t] = s > 0.f ? rsqrtf(s) : 0.f;
    }
    __syncthreads();
    for (int idx = t; idx < 10000; idx += 256) {
      int i = idx/100, j = idx%100;
      A2f[idx] = dl[i]*dl[j]*A2f[idx];
    }
    int rp = t >> 2, cg = t & 3;
    int i0 = rp*2, c0 = cg*8;
    bool act = (t < 200);
    for (int L = 0; L < 3; ++L) {
      if (t < 30) { st1[t] = 0.f; st2[t] = 0.f; }
      const float* W = W3030 + 3*900 + L*900;
      for (int idx = t; idx < 960; idx += 256) {
        int k = idx >> 5, c = idx & 31;
        WL[idx] = (c < 30) ? W[k*30 + c] : 0.f;
      }
      __syncthreads();
      if (act) {
        float a0[8] = {0,0,0,0,0,0,0,0}, a1[8] = {0,0,0,0,0,0,0,0};
        for (int k = 0; k < 30; ++k) {
          float xx0 = buf1[i0*30 + k], xx1 = buf1[(i0+1)*30 + k];
          float4 w0 = *(const float4*)&WL[k*32 + c0];
          float4 w1 = *(const float4*)&WL[k*32 + c0 + 4];
          a0[0] += xx0*w0.x; a0[1] += xx0*w0.y; a0[2] += xx0*w0.z; a0[3] += xx0*w0.w;
          a0[4] += xx0*w1.x; a0[5] += xx0*w1.y; a0[6] += xx0*w1.z; a0[7] += xx0*w1.w;
          a1[0] += xx1*w0.x; a1[1] += xx1*w0.y; a1[2] += xx1*w0.z; a1[3] += xx1*w0.w;
          a1[4] += xx1*w1.x; a1[5] += xx1*w1.y; a1[6] += xx1*w1.z; a1[7] += xx1*w1.w;
        }
        float4 s00 = {a0[0],a0[1],a0[2],a0[3]}, s01 = {a0[4],a0[5],a0[6],a0[7]};
        float4 s10 = {a1[0],a1[1],a1[2],a1[3]}, s11v = {a1[4],a1[5],a1[6],a1[7]};
        *(float4*)&buf2[i0*32 + c0]       = s00;
        *(float4*)&buf2[i0*32 + c0 + 4]   = s01;
        *(float4*)&buf2[(i0+1)*32 + c0]   = s10;
        *(float4*)&buf2[(i0+1)*32 + c0+4] = s11v;
      }
      __syncthreads();
      if (act) {
        float z0[8] = {0,0,0,0,0,0,0,0}, z1[8] = {0,0,0,0,0,0,0,0};
        for (int j = 0; j < 100; ++j) {
          float av0 = A2f[i0*100 + j], av1 = A2f[(i0+1)*100 + j];
          float4 t0 = *(const float4*)&buf2[j*32 + c0];
          float4 t1 = *(const float4*)&buf2[j*32 + c0 + 4];
          z0[0] += av0*t0.x; z0[1] += av0*t0.y; z0[2] += av0*t0.z; z0[3] += av0*t0.w;
          z0[4] += av0*t1.x; z0[5] += av0*t1.y; z0[6] += av0*t1.z; z0[7] += av0*t1.w;
          z1[0] += av1*t0.x; z1[1] += av1*t0.y; z1[2] += av1*t0.z; z1[3] += av1*t0.w;
          z1[4] += av1*t1.x; z1[5] += av1*t1.y; z1[6] += av1*t1.z; z1[7] += av1*t1.w;
        }
#pragma unroll
        for (int k = 0; k < 8; ++k) {
          int c = c0 + k;
          if (c < 30) {
            buf1[i0*30 + c]     = z0[k];
            buf1[(i0+1)*30 + c] = z1[k];
            atomicAdd(&st1[c], z0[k] + z1[k]);
            atomicAdd(&st2[c], z0[k]*z0[k] + z1[k]*z1[k]);
          }
        }
      }
      __syncthreads();
      if (t < 30) {
        atomicAdd(&bktS2[(L*30+t)*2],   st1[t]);
        atomicAdd(&bktS2[(L*30+t)*2+1], st2[t]);
      }
      __syncthreads();
      if (t == 0) {
        __threadfence();
        atomicAdd(cnt2, 1);
        while (atomicAdd(cnt2, 0) < (L+1)*8) {}
        __threadfence();
      }
      __syncthreads();
      if (t < 30) {
        float s1 = atomicAdd(&bktS2[(L*30+t)*2],   0.f);
        float s2 = atomicAdd(&bktS2[(L*30+t)*2+1], 0.f);
        float mean = s1/800.f, var = s2/800.f - mean*mean, inv = rsqrtf(var + 1e-5f);
        float aa = g30[150+L*30+t]*inv;
        coef[t] = aa; coef[30+t] = be30[150+L*30+t] - mean*aa;
      }
      __syncthreads();
      if (L < 2) {
        for (int idx = t; idx < 3000; idx += 256) {
          int c = idx % 30;
          buf1[idx] = coef[c]*buf1[idx] + coef[30+c];
        }
        __syncthreads();
        if (t < 30) {
          float m = -3.4e38f;
          for (int i = 0; i < 100; ++i) m = fmaxf(m, buf1[i*30+t]);
          x2L[L*30+t] = m;
        }
        __syncthreads();
      } else {
        if (t < 30) {
          float m = -3.4e38f;
          for (int i = 0; i < 100; ++i) m = fmaxf(m, coef[t]*buf1[i*30+t] + coef[30+t]);
          x2L[60+t] = m;
        }
      }
    }
    if (t < 90) {
      float m = -3.4e38f;
      for (int s = 0; s < 8; ++s) m = fmaxf(m, partmax[(size_t)(b*8+s)*90 + t]);
      x1L[t] = m;
    }
    __syncthreads();
    if (t < 50) {
      float a = b1[t];
      for (int k = 0; k < 90; ++k) a += x1L[k]*W1[k*50+t];
      for (int k = 0; k < 90; ++k) a += x2L[k]*W1[(90+k)*50+t];
      hh[t] = fmaxf(a, 0.f);
    }
    __syncthreads();
    if (t < 6) {
      float a = b2[t];
      for (int j = 0; j < 50; ++j) a += hh[j]*W2[j*6+t];
      out[b*6+t] = a;
    }
  }
}

// ---------------- launcher ----------------
extern "C" void kernel_launch(void* const* d_in, const int* in_sizes, int n_in,
                              void* d_out, int out_size, void* d_ws, size_t ws_size,
                              hipStream_t stream)
{
  const float* x    = (const float*)d_in[0];
  const float* adj  = (const float*)d_in[1];
  const float* Win  = (const float*)d_in[2];
  const float* W3030= (const float*)d_in[3];
  const float* Wp13 = (const float*)d_in[4];
  // d_in[5]=b30, d_in[6]=b100: cancel through training-mode BN -> unused
  const float* Wfc  = (const float*)d_in[7];
  const float* bfc  = (const float*)d_in[8];
  const float* W1   = (const float*)d_in[9];
  const float* b1   = (const float*)d_in[10];
  const float* W2   = (const float*)d_in[11];
  const float* b2   = (const float*)d_in[12];
  const float* g30  = (const float*)d_in[13];
  const float* be30 = (const float*)d_in[14];
  const float* g100 = (const float*)d_in[15];
  const float* be100= (const float*)d_in[16];
  float* wsf = (float*)d_ws;

  // zero buckets + barrier counters (separate dispatch -> L1 boundary flush)
  hipMemsetAsync(wsf, 0, ZEND * sizeof(float), stream);
  // single persistent kernel: 512 blocks = 2/CU co-resident (70.7 KB LDS each)
  k_mega<<<NBLK, 256, 0, stream>>>(adj, x, Win, W3030, Wp13, Wfc, bfc,
                                   W1, b1, W2, b2, g30, be30, g100, be100,
                                   wsf, (float*)d_out);
}

// Round 12
// 667.399 us; speedup vs baseline: 1.8279x; 1.8279x over previous
//
#include <hip/hip_runtime.h>
#include <hip/hip_fp16.h>
#include <cstdint>
#include <cstddef>

#define BATCH 8
#define NN 2048
#define RTOT 16384   // BATCH*NN
#define CAP 176      // ELL row capacity

// ---------------- workspace layout (offsets in floats) ----------------
// Bucket regions + barrier counters live at the front, zeroed by k_build_ell.
static constexpr size_t OF_B1W   = 0;         // [30][64][2]
static constexpr size_t OF_B1B   = 3840;
static constexpr size_t OF_B2W   = 7680;
static constexpr size_t OF_B2B   = 11520;
static constexpr size_t OF_B3W   = 15360;     // [30][8][2]
static constexpr size_t OF_B3B   = 15840;     // [100][8][2]
static constexpr size_t OF_S2    = 17440;     // [3][30][2]
static constexpr size_t OF_CNT   = 17620;     // int cntA (64-blk barrier), int cntB (s2 barriers)
static constexpr size_t ZEND     = 17632;     // zero range [0, ZEND)
static constexpr size_t OF_ELLV  = 17664;                     // fp32 16384*176
static constexpr size_t OF_ELLC  = OF_ELLV + 2883584;         // u16, 1441792 floats
static constexpr size_t OF_ROWLEN= OF_ELLC + 1441792;
static constexpr size_t OF_DINVW = OF_ROWLEN + 16384;
static constexpr size_t OF_DINVB = OF_DINVW + 16384;
static constexpr size_t OF_HWB   = OF_DINVB + 16384;          // fp16 [RTOT][64]  = 524288 floats
static constexpr size_t OF_HW3   = OF_HWB + 524288;           // fp16 [RTOT][32]  = 262144 floats
static constexpr size_t OF_HB100 = OF_HW3 + 262144;           // fp16 [RTOT][104] = 851968 floats (reused as S)
static constexpr size_t OF_ZW    = OF_HB100 + 851968;         // fp32 stride 32
static constexpr size_t OF_ZB    = OF_ZW + 524288;            // fp32 stride 104 (reused as As)
static constexpr size_t OF_X11   = OF_ZB + 1703936;           // fp32 stride 32
static constexpr size_t OF_X12   = OF_X11 + 524288;
static constexpr size_t OF_X13   = OF_X12 + 524288;
static constexpr size_t OF_S11   = OF_X13 + 524288;           // s11+s12 reused as pool partials pp
static constexpr size_t OF_S12   = OF_S11 + 524288;
static constexpr size_t OF_PARTMAX = OF_S12 + 524288;         // 64*90

#define FMA4(acc, s, h) { acc.x += (s)*(h).x; acc.y += (s)*(h).y; acc.z += (s)*(h).z; acc.w += (s)*(h).w; }

__device__ __forceinline__ unsigned short f2h(float f) {
  _Float16 h = (_Float16)f;
  return *(unsigned short*)&h;
}
__device__ __forceinline__ float h2f(unsigned short s) {
  _Float16 h = *(_Float16*)&s;
  return (float)h;
}
__device__ __forceinline__ float2 h2f2(unsigned int u) {
  __half2 h = *(__half2*)&u;
  return __half22float2(h);
}

struct __align__(8) us4 { unsigned short x, y, z, w; };

// accumulate 8 fp16 channels (one uint4 = 8 fp16) into acc[8] with weight wt
#define ACC8(g, wt) { \
  float2 f0=h2f2((g).x), f1=h2f2((g).y), f2=h2f2((g).z), f3=h2f2((g).w); \
  acc[0] += (wt)*f0.x; acc[1] += (wt)*f0.y; acc[2] += (wt)*f1.x; acc[3] += (wt)*f1.y; \
  acc[4] += (wt)*f2.x; acc[5] += (wt)*f2.y; acc[6] += (wt)*f3.x; acc[7] += (wt)*f3.y; }

// ---------------- kernels ----------------

// One pass over adj: zero bucket/counter region, build ELL (scan-based compaction),
// degrees, FUSED H1 (fp16 interleaved [row][64]).
__global__ __launch_bounds__(256) void k_build_ell(
    const float* __restrict__ adj, const float* __restrict__ x,
    const float* __restrict__ Win, float* __restrict__ ellv,
    unsigned short* __restrict__ ellc, int* __restrict__ rowlen,
    float* __restrict__ dinvw, float* __restrict__ dinvb,
    unsigned short* __restrict__ Hwb, float* __restrict__ zbase)
{
  int r = blockIdx.x;
  int t = threadIdx.x, lane = t & 63, wv = t >> 6;
  if (blockIdx.x < 69) {
    int zi = blockIdx.x * 256 + t;
    if (zi < (int)ZEND) zbase[zi] = 0.f;
  }
  const float* row = adj + (size_t)r * NN;
  __shared__ int wcnt[4];
  __shared__ float wsumA[4];
  __shared__ float dsh[2];
  float4 a = ((const float4*)row)[t];
  float4 b = ((const float4*)row)[256 + t];
  float vals[8] = {a.x, a.y, a.z, a.w, b.x, b.y, b.z, b.w};
  int cbase0 = t*4, cbase1 = 1024 + t*4;
  int cnt = 0; float sum = 0.f;
#pragma unroll
  for (int k = 0; k < 8; ++k) { sum += vals[k]; cnt += (vals[k] != 0.f) ? 1 : 0; }
  int pre = cnt;
#pragma unroll
  for (int o = 1; o < 64; o <<= 1) { int n = __shfl_up(pre, o); if (lane >= o) pre += n; }
  int excl = pre - cnt;
  int wtot = __shfl(pre, 63);
#pragma unroll
  for (int o = 32; o; o >>= 1) sum += __shfl_down(sum, o);
  if (lane == 0) { wcnt[wv] = wtot; wsumA[wv] = sum; }
  __syncthreads();
  int base = 0;
  for (int w = 0; w < wv; ++w) base += wcnt[w];
  int p = base + excl;
  size_t rb = (size_t)r * CAP;
#pragma unroll
  for (int k = 0; k < 8; ++k) {
    float v = vals[k];
    if (v != 0.f && p < CAP) {
      ellv[rb + p] = v;
      ellc[rb + p] = (unsigned short)((k < 4) ? (cbase0 + k) : (cbase1 + (k - 4)));
      ++p;
    }
  }
  if (t == 0) {
    int tot = wcnt[0] + wcnt[1] + wcnt[2] + wcnt[3];
    float ws = wsumA[0] + wsumA[1] + wsumA[2] + wsumA[3];
    int nnz = tot < CAP ? tot : CAP;
    int n = nnz;
    while ((n & 3) && n < CAP) { ellv[rb + n] = 0.f; ellc[rb + n] = 0; ++n; }
    rowlen[r] = n;
    float dw = rsqrtf(ws + 1.f), db = rsqrtf((float)nnz + 1.f);
    dinvw[r] = dw; dinvb[r] = db;
    dsh[0] = dw; dsh[1] = db;
  }
  __syncthreads();
  if (t < 64) {
    int c = t & 31, side = t >> 5;
    float v = 0.f;
    if (c < 30) {
      float x0 = x[r*3], x1 = x[r*3+1], x2 = x[r*3+2];
      const float* W = Win + side*90;
      v = (x0*W[c] + x1*W[30+c] + x2*W[60+c]) * dsh[side];
    }
    Hwb[(size_t)r*64 + t] = f2h(v);
  }
}

// Fused SpMM pair (levels 1,2), fp16 interleaved source. BN stats -> atomic buckets
// laid out [ch][64 copies][2], copy = blockIdx & 63.
__global__ __launch_bounds__(256) void k_spmm_pair(
    const unsigned short* __restrict__ Hwb, const float* __restrict__ ellv,
    const unsigned short* __restrict__ ellc, const int* __restrict__ rowlen,
    const float* __restrict__ dinvw, const float* __restrict__ dinvb,
    float* __restrict__ Zw, float* __restrict__ Zb,
    float* __restrict__ bktW, float* __restrict__ bktB)
{
  __shared__ float zsW[32][32];
  __shared__ float zsB[32][32];
  int t = threadIdx.x;
  int gid = blockIdx.x * 256 + t;   // RTOT*8
  int row = gid >> 3, q = gid & 7;
  int side = q >> 2, sub = q & 3;
  int len = rowlen[row];
  const float4* ev = (const float4*)(ellv + (size_t)row * CAP);
  const uint2*  ec = (const uint2*) (ellc + (size_t)row * CAP);
  const uint4* HP = (const uint4*)(Hwb + (size_t)(row >> 11) * (NN*64));
  float acc[8] = {0,0,0,0,0,0,0,0};
  int nit = len >> 2;
  for (int i = 0; i < nit; ++i) {
    float4 v = ev[i];
    uint2 cc = ec[i];
    int c0 = cc.x & 0xffff, c1 = cc.x >> 16, c2 = cc.y & 0xffff, c3 = cc.y >> 16;
    uint4 g0 = HP[c0*8+q], g1 = HP[c1*8+q], g2 = HP[c2*8+q], g3 = HP[c3*8+q];
    float w0 = side ? (v.x>0.f?1.f:0.f) : v.x;
    float w1 = side ? (v.y>0.f?1.f:0.f) : v.y;
    float w2 = side ? (v.z>0.f?1.f:0.f) : v.z;
    float w3 = side ? (v.w>0.f?1.f:0.f) : v.w;
    ACC8(g0, w0); ACC8(g1, w1); ACC8(g2, w2); ACC8(g3, w3);
  }
  uint4 hs = HP[(row & (NN-1))*8 + q];
  ACC8(hs, 1.f);
  float d = side ? dinvb[row] : dinvw[row];
#pragma unroll
  for (int k = 0; k < 8; ++k) acc[k] *= d;
  float* Zp = (side ? Zb : Zw) + (size_t)row*32 + sub*8;
  float4 o0 = {acc[0],acc[1],acc[2],acc[3]}, o1 = {acc[4],acc[5],acc[6],acc[7]};
  ((float4*)Zp)[0] = o0; ((float4*)Zp)[1] = o1;
  int rowloc = t >> 3;
  float (*zs)[32] = side ? zsB : zsW;
#pragma unroll
  for (int k = 0; k < 8; ++k) zs[rowloc][sub*8+k] = acc[k];
  __syncthreads();
  int copy = blockIdx.x & 63;
  if (t < 30) {
    float s1 = 0.f, s2 = 0.f;
    for (int r = 0; r < 32; ++r) { float v = zsW[r][t]; s1 += v; s2 += v*v; }
    atomicAdd(&bktW[(t*64+copy)*2],   s1);
    atomicAdd(&bktW[(t*64+copy)*2+1], s2);
  } else if (t >= 64 && t < 94) {
    int c = t - 64;
    float s1 = 0.f, s2 = 0.f;
    for (int r = 0; r < 32; ++r) { float v = zsB[r][c]; s1 += v; s2 += v*v; }
    atomicAdd(&bktB[(c*64+copy)*2],   s1);
    atomicAdd(&bktB[(c*64+copy)*2+1], s2);
  }
}

// Level-3 merged SpMM: blocks [0,256) w-side, [256,1088) b-side.
__global__ __launch_bounds__(256) void k_spmm_l3(
    const unsigned short* __restrict__ Hw3, const unsigned short* __restrict__ Hb100,
    const float* __restrict__ ellv, const unsigned short* __restrict__ ellc,
    const int* __restrict__ rowlen, const float* __restrict__ dinvw,
    const float* __restrict__ dinvb, float* __restrict__ Zw, float* __restrict__ Zb,
    float* __restrict__ bktW3, float* __restrict__ bktB3)
{
  __shared__ float zs[64][32];
  __shared__ float st[200];
  int t = threadIdx.x;
  if (blockIdx.x < 256) {
    int gid = blockIdx.x * 256 + t;   // RTOT*4
    int row = gid >> 2, q = gid & 3;
    int len = rowlen[row];
    const float4* ev = (const float4*)(ellv + (size_t)row * CAP);
    const uint2*  ec = (const uint2*) (ellc + (size_t)row * CAP);
    const uint4* HP = (const uint4*)(Hw3 + (size_t)(row >> 11) * (NN*32));
    float acc[8] = {0,0,0,0,0,0,0,0};
    int nit = len >> 2;
    for (int i = 0; i < nit; ++i) {
      float4 v = ev[i];
      uint2 cc = ec[i];
      int c0 = cc.x & 0xffff, c1 = cc.x >> 16, c2 = cc.y & 0xffff, c3 = cc.y >> 16;
      uint4 g0 = HP[c0*4+q], g1 = HP[c1*4+q], g2 = HP[c2*4+q], g3 = HP[c3*4+q];
      ACC8(g0, v.x); ACC8(g1, v.y); ACC8(g2, v.z); ACC8(g3, v.w);
    }
    uint4 hs = HP[(row & (NN-1))*4 + q];
    ACC8(hs, 1.f);
    float d = dinvw[row];
#pragma unroll
    for (int k = 0; k < 8; ++k) acc[k] *= d;
    float* Zp = Zw + (size_t)row*32 + q*8;
    float4 o0 = {acc[0],acc[1],acc[2],acc[3]}, o1 = {acc[4],acc[5],acc[6],acc[7]};
    ((float4*)Zp)[0] = o0; ((float4*)Zp)[1] = o1;
    int rowloc = t >> 2;
#pragma unroll
    for (int k = 0; k < 8; ++k) zs[rowloc][q*8+k] = acc[k];
    __syncthreads();
    if (t < 30) {
      float s1 = 0.f, s2 = 0.f;
      for (int r = 0; r < 64; ++r) { float v = zs[r][t]; s1 += v; s2 += v*v; }
      int copy = blockIdx.x & 7;
      atomicAdd(&bktW3[(t*8+copy)*2],   s1);
      atomicAdd(&bktW3[(t*8+copy)*2+1], s2);
    }
  } else {
    int bid = blockIdx.x - 256;
    for (int i = t; i < 200; i += 256) st[i] = 0.f;
    __syncthreads();
    int gid = bid * 256 + t;    // RTOT*13 exactly (832*256)
    int row = gid / 13, q = gid - row*13;
    int len = rowlen[row];
    const float4* ev = (const float4*)(ellv + (size_t)row * CAP);
    const uint2*  ec = (const uint2*) (ellc + (size_t)row * CAP);
    const uint4* HP = (const uint4*)(Hb100 + (size_t)(row >> 11) * ((size_t)NN*104));
    float acc[8] = {0,0,0,0,0,0,0,0};
    int nit = len >> 2;
    for (int i = 0; i < nit; ++i) {
      float4 v = ev[i];
      uint2 cc = ec[i];
      int c0 = cc.x & 0xffff, c1 = cc.x >> 16, c2 = cc.y & 0xffff, c3 = cc.y >> 16;
      uint4 g0 = HP[c0*13+q], g1 = HP[c1*13+q], g2 = HP[c2*13+q], g3 = HP[c3*13+q];
      float w0 = (v.x>0.f?1.f:0.f), w1 = (v.y>0.f?1.f:0.f);
      float w2 = (v.z>0.f?1.f:0.f), w3 = (v.w>0.f?1.f:0.f);
      ACC8(g0, w0); ACC8(g1, w1); ACC8(g2, w2); ACC8(g3, w3);
    }
    uint4 hs = HP[(row & (NN-1))*13 + q];
    ACC8(hs, 1.f);
    float d = dinvb[row];
#pragma unroll
    for (int k = 0; k < 8; ++k) acc[k] *= d;
    float* Zp = Zb + (size_t)row*104 + q*8;
    float4 o0 = {acc[0],acc[1],acc[2],acc[3]}, o1 = {acc[4],acc[5],acc[6],acc[7]};
    ((float4*)Zp)[0] = o0; ((float4*)Zp)[1] = o1;
    int c0 = q*8;
#pragma unroll
    for (int k = 0; k < 8; ++k) {
      int ch = c0 + k;
      if (ch < 100) { atomicAdd(&st[ch*2], acc[k]); atomicAdd(&st[ch*2+1], acc[k]*acc[k]); }
    }
    __syncthreads();
    int copy = bid & 7;
    for (int i = t; i < 200; i += 256)
      atomicAdd(&bktB3[((i>>1)*8 + copy)*2 + (i&1)], st[i]);
  }
}

// apply BN (inline bucket reduce) -> store x/s -> next-layer weight GEMM -> fp16 outputs.
template<int LEVEL>
__global__ __launch_bounds__(256) void k_apply_gemm(
    const float* __restrict__ Zw, const float* __restrict__ bktW,
    const float* __restrict__ gW, const float* __restrict__ beW,
    float* __restrict__ xst, const float* __restrict__ Ww,
    const float* __restrict__ dinvw,
    const float* __restrict__ Zb, const float* __restrict__ bktB,
    const float* __restrict__ gB, const float* __restrict__ beB,
    float* __restrict__ sst, const float* __restrict__ Wb,
    const float* __restrict__ dinvb,
    unsigned short* __restrict__ HwOut, unsigned short* __restrict__ HbOut)
{
  constexpr int NGB = (LEVEL == 1) ? 8 : 26;
  constexpr int OSTRIDEB = (LEVEL == 1) ? 32 : 104;
  constexpr int NG = 8 + NGB;
  __shared__ float WwL[30*32];
  __shared__ float WbL[30*OSTRIDEB];
  __shared__ float awL[60], abL[60];
  int t = threadIdx.x;
  if (t < 60) {
    int c = t % 30;
    bool isW = t < 30;
    const float4* p = (const float4*)((isW ? bktW : bktB) + c*128);
    float s1 = 0.f, s2 = 0.f;
#pragma unroll
    for (int k = 0; k < 32; ++k) { float4 v = p[k]; s1 += v.x + v.z; s2 += v.y + v.w; }
    float mean = s1/16384.f, var = s2/16384.f - mean*mean, inv = rsqrtf(var + 1e-5f);
    float aa = (isW ? gW : gB)[c]*inv;
    float* dst = isW ? awL : abL;
    dst[c] = aa; dst[30+c] = (isW ? beW : beB)[c] - mean*aa;
  }
  for (int idx = t; idx < 30*32; idx += 256) {
    int k = idx >> 5, c = idx & 31;
    WwL[idx] = (c < 30) ? Ww[k*30 + c] : 0.f;
  }
  if (LEVEL == 1) {
    for (int idx = t; idx < 30*32; idx += 256) {
      int k = idx >> 5, c = idx & 31;
      WbL[idx] = (c < 30) ? Wb[k*30 + c] : 0.f;
    }
  } else {
    for (int idx = t; idx < 30*OSTRIDEB; idx += 256) {
      int k = idx / OSTRIDEB, j = idx % OSTRIDEB;
      WbL[idx] = (j < 100) ? Wb[k*100 + j] : 0.f;
    }
  }
  __syncthreads();
  int gid = blockIdx.x * 256 + t;
  int row = gid / NG, g = gid % NG;
  if (g < 8) {
    const float4* Z4 = (const float4*)Zw + (size_t)row*8;
    float4 z4[8];
#pragma unroll
    for (int u = 0; u < 8; ++u) z4[u] = Z4[u];
    const float* z = (const float*)z4;
    float4 xv;
    int ch = 4*g;
    xv.x = (ch+0 < 30) ? awL[ch+0]*z[ch+0] + awL[30+ch+0] : 0.f;
    xv.y = (ch+1 < 30) ? awL[ch+1]*z[ch+1] + awL[30+ch+1] : 0.f;
    xv.z = (ch+2 < 30) ? awL[ch+2]*z[ch+2] + awL[30+ch+2] : 0.f;
    xv.w = (ch+3 < 30) ? awL[ch+3]*z[ch+3] + awL[30+ch+3] : 0.f;
    ((float4*)xst)[(size_t)row*8+g] = xv;
    float4 o = {0,0,0,0};
#pragma unroll
    for (int k = 0; k < 30; ++k) {
      float xk = awL[k]*z[k] + awL[30+k];
      float4 w = *(const float4*)(WwL + k*32 + 4*g);
      FMA4(o, xk, w);
    }
    float d = dinvw[row];
    us4 pv = { f2h(d*o.x), f2h(d*o.y), f2h(d*o.z), f2h(d*o.w) };
    unsigned short* dst = (LEVEL == 1) ? (HwOut + (size_t)row*64 + 4*g)
                                       : (HwOut + (size_t)row*32 + 4*g);
    *(us4*)dst = pv;
  } else {
    int gb = g - 8;
    const float4* Z4 = (const float4*)Zb + (size_t)row*8;
    float4 z4[8];
#pragma unroll
    for (int u = 0; u < 8; ++u) z4[u] = Z4[u];
    const float* z = (const float*)z4;
    if (gb < 8) {
      int ch = 4*gb;
      float4 sv;
      sv.x = (ch+0 < 30) ? abL[ch+0]*z[ch+0] + abL[30+ch+0] : 0.f;
      sv.y = (ch+1 < 30) ? abL[ch+1]*z[ch+1] + abL[30+ch+1] : 0.f;
      sv.z = (ch+2 < 30) ? abL[ch+2]*z[ch+2] + abL[30+ch+2] : 0.f;
      sv.w = (ch+3 < 30) ? abL[ch+3]*z[ch+3] + abL[30+ch+3] : 0.f;
      ((float4*)sst)[(size_t)row*8+gb] = sv;
    }
    float4 o = {0,0,0,0};
#pragma unroll
    for (int k = 0; k < 30; ++k) {
      float sk = abL[k]*z[k] + abL[30+k];
      float4 w = *(const float4*)(WbL + k*OSTRIDEB + 4*gb);
      FMA4(o, sk, w);
    }
    float d = dinvb[row];
    us4 pv = { f2h(d*o.x), f2h(d*o.y), f2h(d*o.z), f2h(d*o.w) };
    unsigned short* dst = (LEVEL == 1) ? (HbOut + (size_t)row*64 + 32 + 4*gb)
                                       : (HbOut + (size_t)row*104 + 4*gb);
    *(us4*)dst = pv;
  }
}

// fcpool with inline L3 finalize + fused softmax -> fp16 S [row][104]
__global__ __launch_bounds__(256) void k_fcpool(
    const float* __restrict__ Zw3, const float* __restrict__ bktW3,
    const float* __restrict__ gW3, const float* __restrict__ beW3,
    const float* __restrict__ Zb3, const float* __restrict__ bktB3,
    const float* __restrict__ g100, const float* __restrict__ be100,
    const float* __restrict__ s11, const float* __restrict__ s12,
    const float* __restrict__ Wfc, const float* __restrict__ bfc,
    float* __restrict__ x13, unsigned short* __restrict__ S)
{
  __shared__ float shm[14240];   // feat 64x160 = 10240 | Wl 40x100 = 4000
  __shared__ float aw3[60], ab3[200];
  float* feat = shm;
  float* Wl = shm + 10240;
  int t = threadIdx.x;
  int g0 = blockIdx.x * 64;
  if (t < 30) {
    const float4* p = (const float4*)(bktW3 + t*16);
    float s1 = 0.f, s2 = 0.f;
#pragma unroll
    for (int k = 0; k < 4; ++k) { float4 v = p[k]; s1 += v.x + v.z; s2 += v.y + v.w; }
    float mean = s1/16384.f, var = s2/16384.f - mean*mean, inv = rsqrtf(var + 1e-5f);
    float aa = gW3[t]*inv; aw3[t] = aa; aw3[30+t] = beW3[t] - mean*aa;
  } else if (t >= 64 && t < 164) {
    int c = t - 64;
    const float4* p = (const float4*)(bktB3 + c*16);
    float s1 = 0.f, s2 = 0.f;
#pragma unroll
    for (int k = 0; k < 4; ++k) { float4 v = p[k]; s1 += v.x + v.z; s2 += v.y + v.w; }
    float mean = s1/16384.f, var = s2/16384.f - mean*mean, inv = rsqrtf(var + 1e-5f);
    float aa = g100[c]*inv; ab3[c] = aa; ab3[100+c] = be100[c] - mean*aa;
  }
  __syncthreads();
  for (int idx = t; idx < 64*160; idx += 256) {
    int l = idx / 160, c = idx % 160;
    int g = g0 + l;
    float v;
    if (c < 30) v = s11[(size_t)g*32 + c];
    else if (c < 60) v = s12[(size_t)g*32 + (c-30)];
    else { int k = c - 60; v = ab3[k]*Zb3[(size_t)g*104 + k] + ab3[100 + k]; }
    feat[l*160 + c] = v;
  }
  for (int idx = t; idx < 64*32; idx += 256) {
    int l = idx >> 5, c = idx & 31;
    int g = g0 + l;
    x13[(size_t)g*32+c] = (c < 30) ? aw3[c]*Zw3[(size_t)g*32+c] + aw3[30+c] : 0.f;
  }
  int np = t >> 3, kg = t & 7;
  int n0 = np*2, n1 = np*2 + 1;
  int kbase = kg*12 + (kg < 4 ? kg : 4);
  int klen  = kg < 4 ? 13 : 12;
  float a0[13], a1[13];
#pragma unroll
  for (int j = 0; j < 13; ++j) { a0[j] = 0.f; a1[j] = 0.f; }
  for (int ch = 0; ch < 4; ++ch) {
    __syncthreads();
    for (int idx = t; idx < 4000; idx += 256) {
      int r = idx/100, j = idx%100;
      Wl[r*100 + j] = Wfc[(ch*40 + r)*100 + j];
    }
    __syncthreads();
    for (int kk = 0; kk < 40; ++kk) {
      float f0 = feat[n0*160 + ch*40+kk];
      float f1 = feat[n1*160 + ch*40+kk];
#pragma unroll
      for (int j = 0; j < 13; ++j) {
        if (j < klen) {
          float w = Wl[kk*100 + kbase + j];
          a0[j] += f0*w; a1[j] += f1*w;
        }
      }
    }
  }
  __syncthreads();
  float* sRow = shm;  // reuse as [64][100]
  for (int j = 0; j < klen; ++j) {
    int k = kbase + j;
    sRow[n0*100 + k] = a0[j] + bfc[k];
    sRow[n1*100 + k] = a1[j] + bfc[k];
  }
  __syncthreads();
  int n = t >> 2, part = t & 3;
  int i0 = part*25;
  float m = -3.4e38f;
  for (int i = 0; i < 25; ++i) m = fmaxf(m, sRow[n*100 + i0 + i]);
  m = fmaxf(m, __shfl_xor(m, 1));
  m = fmaxf(m, __shfl_xor(m, 2));
  float ev[25]; float s = 0.f;
  for (int i = 0; i < 25; ++i) { float e = __expf(sRow[n*100 + i0 + i] - m); ev[i] = e; s += e; }
  s += __shfl_xor(s, 1);
  s += __shfl_xor(s, 2);
  float rinv = 1.f / s;
  for (int i = 0; i < 25; ++i) S[(size_t)(g0+n)*104 + i0 + i] = f2h(ev[i] * rinv);
  if (part == 3) {
    S[(size_t)(g0+n)*104 + 100] = 0; S[(size_t)(g0+n)*104 + 101] = 0;
    S[(size_t)(g0+n)*104 + 102] = 0; S[(size_t)(g0+n)*104 + 103] = 0;
  }
}

// As = adj @ S (weighted): fp16 S [row][104], 13 lanes/row.
__global__ __launch_bounds__(256) void k_spmm_as(
    const unsigned short* __restrict__ S, const float* __restrict__ ellv,
    const unsigned short* __restrict__ ellc, const int* __restrict__ rowlen,
    float* __restrict__ Z)
{
  int t = threadIdx.x;
  int gid = blockIdx.x * 256 + t;
  int row = gid / 13, q = gid - row*13;
  int len = rowlen[row];
  const float4* ev = (const float4*)(ellv + (size_t)row * CAP);
  const uint2*  ec = (const uint2*) (ellc + (size_t)row * CAP);
  const uint4* HP = (const uint4*)(S + (size_t)(row >> 11) * ((size_t)NN*104));
  float acc[8] = {0,0,0,0,0,0,0,0};
  int nit = len >> 2;
  for (int i = 0; i < nit; ++i) {
    float4 v = ev[i];
    uint2 cc = ec[i];
    int c0 = cc.x & 0xffff, c1 = cc.x >> 16, c2 = cc.y & 0xffff, c3 = cc.y >> 16;
    uint4 g0 = HP[c0*13+q], g1 = HP[c1*13+q], g2 = HP[c2*13+q], g3 = HP[c3*13+q];
    ACC8(g0, v.x); ACC8(g1, v.y); ACC8(g2, v.z); ACC8(g3, v.w);
  }
  float* Zp = Z + (size_t)row*104 + q*8;
  float4 o0 = {acc[0],acc[1],acc[2],acc[3]}, o1 = {acc[4],acc[5],acc[6],acc[7]};
  ((float4*)Zp)[0] = o0; ((float4*)Zp)[1] = o1;
}

// TAIL: cooperative 64-block kernel = pool_part (+stage-1 max) -> 64-blk barrier ->
// stage-2 on blocks 0..7. Barrier pattern device-validated in R9-R11.
__global__ __launch_bounds__(256) void k_tail(
    const unsigned short* __restrict__ S, const float* __restrict__ x13,
    const float* __restrict__ As, const float* __restrict__ x11,
    const float* __restrict__ x12, float* __restrict__ pp, float* __restrict__ pm,
    const float* __restrict__ Wm, const float* __restrict__ g30s,
    const float* __restrict__ be30s, float* __restrict__ bktS2,
    int* __restrict__ cnt,
    const float* __restrict__ W1, const float* __restrict__ b1,
    const float* __restrict__ W2, const float* __restrict__ b2,
    float* __restrict__ out)
{
  __shared__ float shm[17664];   // 70.6 KB: pool phase uses 15104, s2 phase uses all
  int blk = blockIdx.x, t = threadIdx.x;
  int* cntA = cnt;      // 64-block barrier
  int* cntB = cnt + 1;  // s2 8-block barriers
  // ---- phase A: pooled partials + stage-1 col max ----
  {
    float* sL = shm;            // [64][100]
    float* xL = shm + 6400;     // [64][132]
    float* red = shm + 14848;   // [256]
    int b = blk >> 3, chunk = blk & 7;
    int g00 = b * 2048 + chunk * 256;
    int kt = t/10, dt = t%10;
    int k0 = kt*4, d0 = dt*13;
    float acc[4][13];
#pragma unroll
    for (int a = 0; a < 4; ++a)
#pragma unroll
      for (int j = 0; j < 13; ++j) acc[a][j] = 0.f;
    for (int tile = 0; tile < 4; ++tile) {
      int g0 = g00 + tile*64;
      __syncthreads();
      for (int idx = t; idx < 64*100; idx += 256) {
        int l = idx/100, k = idx%100;
        sL[l*100 + k] = h2f(S[(size_t)(g0+l)*104 + k]);
      }
      for (int idx = t; idx < 64*130; idx += 256) {
        int l = idx/130, d = idx%130;
        xL[l*132 + d] = d < 30 ? x13[(size_t)(g0+l)*32 + d] : As[(size_t)(g0+l)*104 + (d-30)];
      }
      __syncthreads();
      if (t < 250) {
        for (int kk = 0; kk < 64; ++kk) {
          float sv[4];
#pragma unroll
          for (int a = 0; a < 4; ++a) sv[a] = sL[kk*100 + k0+a];
#pragma unroll
          for (int j = 0; j < 13; ++j) {
            float xv = xL[kk*132 + d0+j];
#pragma unroll
            for (int a = 0; a < 4; ++a) acc[a][j] += sv[a]*xv;
          }
        }
      }
    }
    if (t < 250) {
      float* dst = pp + (size_t)blk * 13000;
      for (int a = 0; a < 4; ++a)
        for (int j = 0; j < 13; ++j)
          dst[(k0+a)*130 + (d0+j)] = acc[a][j];
    }
    __syncthreads();
    {
      int c = t & 31, rg = t >> 5;
      const float* srcs[3] = {x11, x12, x13};
      for (int a = 0; a < 3; ++a) {
        const float* p = srcs[a] + (size_t)(g00+rg)*32 + c;
        float m = -3.4e38f;
        for (int it = 0; it < 32; ++it) m = fmaxf(m, p[it*256]);
        red[t] = m;
        __syncthreads();
        if (t < 30) {
          float mm = red[t];
          for (int g = 1; g < 8; ++g) mm = fmaxf(mm, red[g*32+t]);
          pm[(size_t)blk*90 + a*30 + t] = mm;
        }
        __syncthreads();
      }
    }
  }
  // ---- 64-block barrier (all 64 co-resident: 70.6 KB -> 2/CU needs 32 CUs) ----
  __syncthreads();
  if (t == 0) {
    __threadfence();
    atomicAdd(cntA, 1);
    while (atomicAdd(cntA, 0) < 64) {}
    __threadfence();
  }
  __syncthreads();
  if (blk >= 8) return;
  // ---- phase B: stage 2 (register-tiled, fp32 A2 in LDS) ----
  {
    float* A2f  = shm;            // 10000
    float* buf1 = shm + 10000;    // 3000
    float* buf2 = shm + 13000;    // 3200 (T padded [100][32])
    float* WL   = shm + 16200;    // 960
    float* dl   = shm + 17160;    // 100
    float* st1  = shm + 17260;    // 30
    float* st2  = shm + 17290;    // 30
    float* coef = shm + 17320;    // 60
    float* x1L  = shm + 17380;    // 90
    float* x2L  = shm + 17470;    // 90
    float* hh   = shm + 17560;    // 50
    int b = blk;
    __syncthreads();
    for (int idx = t; idx < 13000; idx += 256) {
      float s = 0.f;
      for (int ch = 0; ch < 8; ++ch) s += pp[(size_t)(b*8 + ch)*13000 + idx];
      int k = idx/130, d = idx%130;
      if (d < 30) buf1[k*30 + d] = s;
      else A2f[k*100 + (d-30)] = s;
    }
    __syncthreads();
    if (t < 100 && A2f[t*101] == 0.f) A2f[t*101] = 1.f;
    __syncthreads();
    if (t < 100) {
      float s = 0.f;
      for (int j = 0; j < 100; ++j) s += A2f[t*100 + j];
      dl[t] = s > 0.f ? rsqrtf(s) : 0.f;
    }
    __syncthreads();
    for (int idx = t; idx < 10000; idx += 256) {
      int i = idx/100, j = idx%100;
      A2f[idx] = dl[i]*dl[j]*A2f[idx];
    }
    int rp = t >> 2, cg = t & 3;
    int i0 = rp*2, c0 = cg*8;
    bool act = (t < 200);
    for (int L = 0; L < 3; ++L) {
      if (t < 30) { st1[t] = 0.f; st2[t] = 0.f; }
      const float* W = Wm + L*900;
      for (int idx = t; idx < 960; idx += 256) {
        int k = idx >> 5, c = idx & 31;
        WL[idx] = (c < 30) ? W[k*30 + c] : 0.f;
      }
      __syncthreads();
      if (act) {
        float a0[8] = {0,0,0,0,0,0,0,0}, a1[8] = {0,0,0,0,0,0,0,0};
        for (int k = 0; k < 30; ++k) {
          float xx0 = buf1[i0*30 + k], xx1 = buf1[(i0+1)*30 + k];
          float4 w0 = *(const float4*)&WL[k*32 + c0];
          float4 w1 = *(const float4*)&WL[k*32 + c0 + 4];
          a0[0] += xx0*w0.x; a0[1] += xx0*w0.y; a0[2] += xx0*w0.z; a0[3] += xx0*w0.w;
          a0[4] += xx0*w1.x; a0[5] += xx0*w1.y; a0[6] += xx0*w1.z; a0[7] += xx0*w1.w;
          a1[0] += xx1*w0.x; a1[1] += xx1*w0.y; a1[2] += xx1*w0.z; a1[3] += xx1*w0.w;
          a1[4] += xx1*w1.x; a1[5] += xx1*w1.y; a1[6] += xx1*w1.z; a1[7] += xx1*w1.w;
        }
        float4 s00 = {a0[0],a0[1],a0[2],a0[3]}, s01 = {a0[4],a0[5],a0[6],a0[7]};
        float4 s10 = {a1[0],a1[1],a1[2],a1[3]}, s11v = {a1[4],a1[5],a1[6],a1[7]};
        *(float4*)&buf2[i0*32 + c0]       = s00;
        *(float4*)&buf2[i0*32 + c0 + 4]   = s01;
        *(float4*)&buf2[(i0+1)*32 + c0]   = s10;
        *(float4*)&buf2[(i0+1)*32 + c0+4] = s11v;
      }
      __syncthreads();
      if (act) {
        float z0[8] = {0,0,0,0,0,0,0,0}, z1[8] = {0,0,0,0,0,0,0,0};
        for (int j = 0; j < 100; ++j) {
          float av0 = A2f[i0*100 + j], av1 = A2f[(i0+1)*100 + j];
          float4 t0 = *(const float4*)&buf2[j*32 + c0];
          float4 t1 = *(const float4*)&buf2[j*32 + c0 + 4];
          z0[0] += av0*t0.x; z0[1] += av0*t0.y; z0[2] += av0*t0.z; z0[3] += av0*t0.w;
          z0[4] += av0*t1.x; z0[5] += av0*t1.y; z0[6] += av0*t1.z; z0[7] += av0*t1.w;
          z1[0] += av1*t0.x; z1[1] += av1*t0.y; z1[2] += av1*t0.z; z1[3] += av1*t0.w;
          z1[4] += av1*t1.x; z1[5] += av1*t1.y; z1[6] += av1*t1.z; z1[7] += av1*t1.w;
        }
#pragma unroll
        for (int k = 0; k < 8; ++k) {
          int c = c0 + k;
          if (c < 30) {
            buf1[i0*30 + c]     = z0[k];
            buf1[(i0+1)*30 + c] = z1[k];
            atomicAdd(&st1[c], z0[k] + z1[k]);
            atomicAdd(&st2[c], z0[k]*z0[k] + z1[k]*z1[k]);
          }
        }
      }
      __syncthreads();
      if (t < 30) {
        atomicAdd(&bktS2[(L*30+t)*2],   st1[t]);
        atomicAdd(&bktS2[(L*30+t)*2+1], st2[t]);
      }
      __syncthreads();
      if (t == 0) {
        __threadfence();
        atomicAdd(cntB, 1);
        while (atomicAdd(cntB, 0) < (L+1)*8) {}
        __threadfence();
      }
      __syncthreads();
      if (t < 30) {
        float s1 = atomicAdd(&bktS2[(L*30+t)*2],   0.f);
        float s2 = atomicAdd(&bktS2[(L*30+t)*2+1], 0.f);
        float mean = s1/800.f, var = s2/800.f - mean*mean, inv = rsqrtf(var + 1e-5f);
        float aa = g30s[L*30+t]*inv;
        coef[t] = aa; coef[30+t] = be30s[L*30+t] - mean*aa;
      }
      __syncthreads();
      if (L < 2) {
        for (int idx = t; idx < 3000; idx += 256) {
          int c = idx % 30;
          buf1[idx] = coef[c]*buf1[idx] + coef[30+c];
        }
        __syncthreads();
        if (t < 30) {
          float m = -3.4e38f;
          for (int i = 0; i < 100; ++i) m = fmaxf(m, buf1[i*30+t]);
          x2L[L*30+t] = m;
        }
        __syncthreads();
      } else {
        if (t < 30) {
          float m = -3.4e38f;
          for (int i = 0; i < 100; ++i) m = fmaxf(m, coef[t]*buf1[i*30+t] + coef[30+t]);
          x2L[60+t] = m;
        }
      }
    }
    if (t < 90) {
      float m = -3.4e38f;
      for (int s = 0; s < 8; ++s) m = fmaxf(m, pm[(size_t)(b*8+s)*90 + t]);
      x1L[t] = m;
    }
    __syncthreads();
    if (t < 50) {
      float a = b1[t];
      for (int k = 0; k < 90; ++k) a += x1L[k]*W1[k*50+t];
      for (int k = 0; k < 90; ++k) a += x2L[k]*W1[(90+k)*50+t];
      hh[t] = fmaxf(a, 0.f);
    }
    __syncthreads();
    if (t < 6) {
      float a = b2[t];
      for (int j = 0; j < 50; ++j) a += hh[j]*W2[j*6+t];
      out[b*6+t] = a;
    }
  }
}

// ---------------- launcher ----------------
extern "C" void kernel_launch(void* const* d_in, const int* in_sizes, int n_in,
                              void* d_out, int out_size, void* d_ws, size_t ws_size,
                              hipStream_t stream)
{
  const float* x    = (const float*)d_in[0];
  const float* adj  = (const float*)d_in[1];
  const float* Win  = (const float*)d_in[2];
  const float* W3030= (const float*)d_in[3];
  const float* Wp13 = (const float*)d_in[4];
  // d_in[5]=b30, d_in[6]=b100: cancel through training-mode BN -> unused
  const float* Wfc  = (const float*)d_in[7];
  const float* bfc  = (const float*)d_in[8];
  const float* W1   = (const float*)d_in[9];
  const float* b1   = (const float*)d_in[10];
  const float* W2   = (const float*)d_in[11];
  const float* b2   = (const float*)d_in[12];
  const float* g30  = (const float*)d_in[13];
  const float* be30 = (const float*)d_in[14];
  const float* g100 = (const float*)d_in[15];
  const float* be100= (const float*)d_in[16];
  float* out = (float*)d_out;

  float* wsf = (float*)d_ws;
  float* bL1W = wsf + OF_B1W;  float* bL1B = wsf + OF_B1B;
  float* bL2W = wsf + OF_B2W;  float* bL2B = wsf + OF_B2B;
  float* bL3W = wsf + OF_B3W;  float* bL3B = wsf + OF_B3B;
  float* bktS2 = wsf + OF_S2;
  int*   cnt  = (int*)(wsf + OF_CNT);
  float* ellv  = wsf + OF_ELLV;
  unsigned short* ellc = (unsigned short*)(wsf + OF_ELLC);
  int*   rowlen = (int*)(wsf + OF_ROWLEN);
  float* dinvw = wsf + OF_DINVW;
  float* dinvb = wsf + OF_DINVB;
  unsigned short* Hwb   = (unsigned short*)(wsf + OF_HWB);
  unsigned short* Hw3   = (unsigned short*)(wsf + OF_HW3);
  unsigned short* Hb100 = (unsigned short*)(wsf + OF_HB100);
  unsigned short* S     = Hb100;   // S reuses HB100 (dead after L3-b spmm)
  float* Zw = wsf + OF_ZW;
  float* Zb = wsf + OF_ZB;         // stride 104; later reused as As
  float* x11 = wsf + OF_X11;
  float* x12 = wsf + OF_X12;
  float* x13 = wsf + OF_X13;
  float* s11 = wsf + OF_S11;
  float* s12 = wsf + OF_S12;
  float* pp  = wsf + OF_S11;       // pool partials reuse s11+s12 (dead after fcpool)
  float* partmax = wsf + OF_PARTMAX;

  // 9 dispatches (R12: revert from R11 mega-kernel — 2 blk/CU starved the gather
  // SpMMs of TLP, 656 -> 1220; only the LDS-heavy tail phases tolerate 2/CU).
  k_build_ell<<<RTOT, 256, 0, stream>>>(adj, x, Win, ellv, ellc, rowlen, dinvw, dinvb, Hwb, wsf);

  k_spmm_pair<<<512, 256, 0, stream>>>(Hwb, ellv, ellc, rowlen, dinvw, dinvb, Zw, Zb, bL1W, bL1B);
  k_apply_gemm<1><<<1024, 256, 0, stream>>>(Zw, bL1W, g30+0, be30+0, x11, W3030+0, dinvw,
                                            Zb, bL1B, g30+90, be30+90, s11, W3030+2*900, dinvb, Hwb, Hwb);

  k_spmm_pair<<<512, 256, 0, stream>>>(Hwb, ellv, ellc, rowlen, dinvw, dinvb, Zw, Zb, bL2W, bL2B);
  k_apply_gemm<2><<<2176, 256, 0, stream>>>(Zw, bL2W, g30+30, be30+30, x12, W3030+900, dinvw,
                                            Zb, bL2B, g30+120, be30+120, s12, Wp13, dinvb, Hw3, Hb100);

  k_spmm_l3<<<1088, 256, 0, stream>>>(Hw3, Hb100, ellv, ellc, rowlen, dinvw, dinvb, Zw, Zb, bL3W, bL3B);
  k_fcpool<<<256, 256, 0, stream>>>(Zw, bL3W, g30+60, be30+60, Zb, bL3B, g100, be100,
                                    s11, s12, Wfc, bfc, x13, S);

  k_spmm_as<<<832, 256, 0, stream>>>(S, ellv, ellc, rowlen, Zb /* As */);
  k_tail<<<64, 256, 0, stream>>>(S, x13, Zb, x11, x12, pp, partmax,
                                 W3030+3*900, g30+150, be30+150, bktS2, cnt,
                                 W1, b1, W2, b2, out);
}

// Round 13
// 656.466 us; speedup vs baseline: 1.8583x; 1.0167x over previous
//
#include <hip/hip_runtime.h>
#include <hip/hip_fp16.h>
#include <cstdint>
#include <cstddef>

#define BATCH 8
#define NN 2048
#define RTOT 16384   // BATCH*NN
#define CAP 176      // ELL row capacity

// ---------------- workspace layout (offsets in floats) ----------------
static constexpr size_t OF_B1W   = 0;         // [30][64][2]
static constexpr size_t OF_B1B   = 3840;
static constexpr size_t OF_B2W   = 7680;
static constexpr size_t OF_B2B   = 11520;
static constexpr size_t OF_B3W   = 15360;     // [30][8][2]
static constexpr size_t OF_B3B   = 15840;     // [100][8][2]
static constexpr size_t OF_S2    = 17440;     // [3][30][2]
static constexpr size_t OF_CNT   = 17620;     // int cntA (64-blk barrier), int cntB (s2 barriers)
static constexpr size_t ZEND     = 17632;     // zero range [0, ZEND)
static constexpr size_t OF_ELLV  = 17664;                     // fp32 16384*176
static constexpr size_t OF_ELLC  = OF_ELLV + 2883584;         // u16, 1441792 floats
static constexpr size_t OF_ROWLEN= OF_ELLC + 1441792;
static constexpr size_t OF_DINVW = OF_ROWLEN + 16384;
static constexpr size_t OF_DINVB = OF_DINVW + 16384;
static constexpr size_t OF_HWB   = OF_DINVB + 16384;          // fp16 [RTOT][64]  = 524288 floats
static constexpr size_t OF_HW3   = OF_HWB + 524288;           // fp16 [RTOT][32]  = 262144 floats
static constexpr size_t OF_HB100 = OF_HW3 + 262144;           // fp16 [RTOT][104] = 851968 floats (reused as S)
static constexpr size_t OF_ZW    = OF_HB100 + 851968;         // fp32 stride 32
static constexpr size_t OF_ZB    = OF_ZW + 524288;            // fp32 stride 104 (reused as As)
static constexpr size_t OF_X11   = OF_ZB + 1703936;           // fp32 stride 32
static constexpr size_t OF_X12   = OF_X11 + 524288;
static constexpr size_t OF_X13   = OF_X12 + 524288;
static constexpr size_t OF_S11   = OF_X13 + 524288;           // s11+s12 reused as pool partials pp
static constexpr size_t OF_S12   = OF_S11 + 524288;
static constexpr size_t OF_PARTMAX = OF_S12 + 524288;         // 64*90

#define FMA4(acc, s, h) { acc.x += (s)*(h).x; acc.y += (s)*(h).y; acc.z += (s)*(h).z; acc.w += (s)*(h).w; }

__device__ __forceinline__ unsigned short f2h(float f) {
  _Float16 h = (_Float16)f;
  return *(unsigned short*)&h;
}
__device__ __forceinline__ float h2f(unsigned short s) {
  _Float16 h = *(_Float16*)&s;
  return (float)h;
}
__device__ __forceinline__ float2 h2f2(unsigned int u) {
  __half2 h = *(__half2*)&u;
  return __half22float2(h);
}

struct __align__(8) us4 { unsigned short x, y, z, w; };

// accumulate 8 fp16 channels (one uint4 = 8 fp16) into acc[8] with weight wt
#define ACC8(g, wt) { \
  float2 f0=h2f2((g).x), f1=h2f2((g).y), f2=h2f2((g).z), f3=h2f2((g).w); \
  acc[0] += (wt)*f0.x; acc[1] += (wt)*f0.y; acc[2] += (wt)*f1.x; acc[3] += (wt)*f1.y; \
  acc[4] += (wt)*f2.x; acc[5] += (wt)*f2.y; acc[6] += (wt)*f3.x; acc[7] += (wt)*f3.y; }

// ---------------- kernels ----------------

// One pass over adj: zero bucket/counter region, build ELL (scan-based compaction),
// degrees, FUSED H1 (fp16 interleaved [row][64]).
__global__ __launch_bounds__(256) void k_build_ell(
    const float* __restrict__ adj, const float* __restrict__ x,
    const float* __restrict__ Win, float* __restrict__ ellv,
    unsigned short* __restrict__ ellc, int* __restrict__ rowlen,
    float* __restrict__ dinvw, float* __restrict__ dinvb,
    unsigned short* __restrict__ Hwb, float* __restrict__ zbase)
{
  int r = blockIdx.x;
  int t = threadIdx.x, lane = t & 63, wv = t >> 6;
  if (blockIdx.x < 69) {
    int zi = blockIdx.x * 256 + t;
    if (zi < (int)ZEND) zbase[zi] = 0.f;
  }
  const float* row = adj + (size_t)r * NN;
  __shared__ int wcnt[4];
  __shared__ float wsumA[4];
  __shared__ float dsh[2];
  float4 a = ((const float4*)row)[t];
  float4 b = ((const float4*)row)[256 + t];
  float vals[8] = {a.x, a.y, a.z, a.w, b.x, b.y, b.z, b.w};
  int cbase0 = t*4, cbase1 = 1024 + t*4;
  int cnt = 0; float sum = 0.f;
#pragma unroll
  for (int k = 0; k < 8; ++k) { sum += vals[k]; cnt += (vals[k] != 0.f) ? 1 : 0; }
  int pre = cnt;
#pragma unroll
  for (int o = 1; o < 64; o <<= 1) { int n = __shfl_up(pre, o); if (lane >= o) pre += n; }
  int excl = pre - cnt;
  int wtot = __shfl(pre, 63);
#pragma unroll
  for (int o = 32; o; o >>= 1) sum += __shfl_down(sum, o);
  if (lane == 0) { wcnt[wv] = wtot; wsumA[wv] = sum; }
  __syncthreads();
  int base = 0;
  for (int w = 0; w < wv; ++w) base += wcnt[w];
  int p = base + excl;
  size_t rb = (size_t)r * CAP;
#pragma unroll
  for (int k = 0; k < 8; ++k) {
    float v = vals[k];
    if (v != 0.f && p < CAP) {
      ellv[rb + p] = v;
      ellc[rb + p] = (unsigned short)((k < 4) ? (cbase0 + k) : (cbase1 + (k - 4)));
      ++p;
    }
  }
  if (t == 0) {
    int tot = wcnt[0] + wcnt[1] + wcnt[2] + wcnt[3];
    float ws = wsumA[0] + wsumA[1] + wsumA[2] + wsumA[3];
    int nnz = tot < CAP ? tot : CAP;
    int n = nnz;
    while ((n & 3) && n < CAP) { ellv[rb + n] = 0.f; ellc[rb + n] = 0; ++n; }
    rowlen[r] = n;
    float dw = rsqrtf(ws + 1.f), db = rsqrtf((float)nnz + 1.f);
    dinvw[r] = dw; dinvb[r] = db;
    dsh[0] = dw; dsh[1] = db;
  }
  __syncthreads();
  if (t < 64) {
    int c = t & 31, side = t >> 5;
    float v = 0.f;
    if (c < 30) {
      float x0 = x[r*3], x1 = x[r*3+1], x2 = x[r*3+2];
      const float* W = Win + side*90;
      v = (x0*W[c] + x1*W[30+c] + x2*W[60+c]) * dsh[side];
    }
    Hwb[(size_t)r*64 + t] = f2h(v);
  }
}

// Fused SpMM pair (levels 1,2), fp16 interleaved source. BN stats -> atomic buckets.
__global__ __launch_bounds__(256) void k_spmm_pair(
    const unsigned short* __restrict__ Hwb, const float* __restrict__ ellv,
    const unsigned short* __restrict__ ellc, const int* __restrict__ rowlen,
    const float* __restrict__ dinvw, const float* __restrict__ dinvb,
    float* __restrict__ Zw, float* __restrict__ Zb,
    float* __restrict__ bktW, float* __restrict__ bktB)
{
  __shared__ float zsW[32][32];
  __shared__ float zsB[32][32];
  int t = threadIdx.x;
  int gid = blockIdx.x * 256 + t;   // RTOT*8
  int row = gid >> 3, q = gid & 7;
  int side = q >> 2, sub = q & 3;
  int len = rowlen[row];
  const float4* ev = (const float4*)(ellv + (size_t)row * CAP);
  const uint2*  ec = (const uint2*) (ellc + (size_t)row * CAP);
  const uint4* HP = (const uint4*)(Hwb + (size_t)(row >> 11) * (NN*64));
  float acc[8] = {0,0,0,0,0,0,0,0};
  int nit = len >> 2;
  for (int i = 0; i < nit; ++i) {
    float4 v = ev[i];
    uint2 cc = ec[i];
    int c0 = cc.x & 0xffff, c1 = cc.x >> 16, c2 = cc.y & 0xffff, c3 = cc.y >> 16;
    uint4 g0 = HP[c0*8+q], g1 = HP[c1*8+q], g2 = HP[c2*8+q], g3 = HP[c3*8+q];
    float w0 = side ? (v.x>0.f?1.f:0.f) : v.x;
    float w1 = side ? (v.y>0.f?1.f:0.f) : v.y;
    float w2 = side ? (v.z>0.f?1.f:0.f) : v.z;
    float w3 = side ? (v.w>0.f?1.f:0.f) : v.w;
    ACC8(g0, w0); ACC8(g1, w1); ACC8(g2, w2); ACC8(g3, w3);
  }
  uint4 hs = HP[(row & (NN-1))*8 + q];
  ACC8(hs, 1.f);
  float d = side ? dinvb[row] : dinvw[row];
#pragma unroll
  for (int k = 0; k < 8; ++k) acc[k] *= d;
  float* Zp = (side ? Zb : Zw) + (size_t)row*32 + sub*8;
  float4 o0 = {acc[0],acc[1],acc[2],acc[3]}, o1 = {acc[4],acc[5],acc[6],acc[7]};
  ((float4*)Zp)[0] = o0; ((float4*)Zp)[1] = o1;
  int rowloc = t >> 3;
  float (*zs)[32] = side ? zsB : zsW;
#pragma unroll
  for (int k = 0; k < 8; ++k) zs[rowloc][sub*8+k] = acc[k];
  __syncthreads();
  int copy = blockIdx.x & 63;
  if (t < 30) {
    float s1 = 0.f, s2 = 0.f;
    for (int r = 0; r < 32; ++r) { float v = zsW[r][t]; s1 += v; s2 += v*v; }
    atomicAdd(&bktW[(t*64+copy)*2],   s1);
    atomicAdd(&bktW[(t*64+copy)*2+1], s2);
  } else if (t >= 64 && t < 94) {
    int c = t - 64;
    float s1 = 0.f, s2 = 0.f;
    for (int r = 0; r < 32; ++r) { float v = zsB[r][c]; s1 += v; s2 += v*v; }
    atomicAdd(&bktB[(c*64+copy)*2],   s1);
    atomicAdd(&bktB[(c*64+copy)*2+1], s2);
  }
}

// Level-3 merged SpMM: blocks [0,256) w-side, [256,1088) b-side.
__global__ __launch_bounds__(256) void k_spmm_l3(
    const unsigned short* __restrict__ Hw3, const unsigned short* __restrict__ Hb100,
    const float* __restrict__ ellv, const unsigned short* __restrict__ ellc,
    const int* __restrict__ rowlen, const float* __restrict__ dinvw,
    const float* __restrict__ dinvb, float* __restrict__ Zw, float* __restrict__ Zb,
    float* __restrict__ bktW3, float* __restrict__ bktB3)
{
  __shared__ float zs[64][32];
  __shared__ float st[200];
  int t = threadIdx.x;
  if (blockIdx.x < 256) {
    int gid = blockIdx.x * 256 + t;   // RTOT*4
    int row = gid >> 2, q = gid & 3;
    int len = rowlen[row];
    const float4* ev = (const float4*)(ellv + (size_t)row * CAP);
    const uint2*  ec = (const uint2*) (ellc + (size_t)row * CAP);
    const uint4* HP = (const uint4*)(Hw3 + (size_t)(row >> 11) * (NN*32));
    float acc[8] = {0,0,0,0,0,0,0,0};
    int nit = len >> 2;
    for (int i = 0; i < nit; ++i) {
      float4 v = ev[i];
      uint2 cc = ec[i];
      int c0 = cc.x & 0xffff, c1 = cc.x >> 16, c2 = cc.y & 0xffff, c3 = cc.y >> 16;
      uint4 g0 = HP[c0*4+q], g1 = HP[c1*4+q], g2 = HP[c2*4+q], g3 = HP[c3*4+q];
      ACC8(g0, v.x); ACC8(g1, v.y); ACC8(g2, v.z); ACC8(g3, v.w);
    }
    uint4 hs = HP[(row & (NN-1))*4 + q];
    ACC8(hs, 1.f);
    float d = dinvw[row];
#pragma unroll
    for (int k = 0; k < 8; ++k) acc[k] *= d;
    float* Zp = Zw + (size_t)row*32 + q*8;
    float4 o0 = {acc[0],acc[1],acc[2],acc[3]}, o1 = {acc[4],acc[5],acc[6],acc[7]};
    ((float4*)Zp)[0] = o0; ((float4*)Zp)[1] = o1;
    int rowloc = t >> 2;
#pragma unroll
    for (int k = 0; k < 8; ++k) zs[rowloc][q*8+k] = acc[k];
    __syncthreads();
    if (t < 30) {
      float s1 = 0.f, s2 = 0.f;
      for (int r = 0; r < 64; ++r) { float v = zs[r][t]; s1 += v; s2 += v*v; }
      int copy = blockIdx.x & 7;
      atomicAdd(&bktW3[(t*8+copy)*2],   s1);
      atomicAdd(&bktW3[(t*8+copy)*2+1], s2);
    }
  } else {
    int bid = blockIdx.x - 256;
    for (int i = t; i < 200; i += 256) st[i] = 0.f;
    __syncthreads();
    int gid = bid * 256 + t;    // RTOT*13 exactly (832*256)
    int row = gid / 13, q = gid - row*13;
    int len = rowlen[row];
    const float4* ev = (const float4*)(ellv + (size_t)row * CAP);
    const uint2*  ec = (const uint2*) (ellc + (size_t)row * CAP);
    const uint4* HP = (const uint4*)(Hb100 + (size_t)(row >> 11) * ((size_t)NN*104));
    float acc[8] = {0,0,0,0,0,0,0,0};
    int nit = len >> 2;
    for (int i = 0; i < nit; ++i) {
      float4 v = ev[i];
      uint2 cc = ec[i];
      int c0 = cc.x & 0xffff, c1 = cc.x >> 16, c2 = cc.y & 0xffff, c3 = cc.y >> 16;
      uint4 g0 = HP[c0*13+q], g1 = HP[c1*13+q], g2 = HP[c2*13+q], g3 = HP[c3*13+q];
      float w0 = (v.x>0.f?1.f:0.f), w1 = (v.y>0.f?1.f:0.f);
      float w2 = (v.z>0.f?1.f:0.f), w3 = (v.w>0.f?1.f:0.f);
      ACC8(g0, w0); ACC8(g1, w1); ACC8(g2, w2); ACC8(g3, w3);
    }
    uint4 hs = HP[(row & (NN-1))*13 + q];
    ACC8(hs, 1.f);
    float d = dinvb[row];
#pragma unroll
    for (int k = 0; k < 8; ++k) acc[k] *= d;
    float* Zp = Zb + (size_t)row*104 + q*8;
    float4 o0 = {acc[0],acc[1],acc[2],acc[3]}, o1 = {acc[4],acc[5],acc[6],acc[7]};
    ((float4*)Zp)[0] = o0; ((float4*)Zp)[1] = o1;
    int c0 = q*8;
#pragma unroll
    for (int k = 0; k < 8; ++k) {
      int ch = c0 + k;
      if (ch < 100) { atomicAdd(&st[ch*2], acc[k]); atomicAdd(&st[ch*2+1], acc[k]*acc[k]); }
    }
    __syncthreads();
    int copy = bid & 7;
    for (int i = t; i < 200; i += 256)
      atomicAdd(&bktB3[((i>>1)*8 + copy)*2 + (i&1)], st[i]);
  }
}

// apply BN (inline bucket reduce) -> store x/s -> next-layer weight GEMM -> fp16 outputs.
template<int LEVEL>
__global__ __launch_bounds__(256) void k_apply_gemm(
    const float* __restrict__ Zw, const float* __restrict__ bktW,
    const float* __restrict__ gW, const float* __restrict__ beW,
    float* __restrict__ xst, const float* __restrict__ Ww,
    const float* __restrict__ dinvw,
    const float* __restrict__ Zb, const float* __restrict__ bktB,
    const float* __restrict__ gB, const float* __restrict__ beB,
    float* __restrict__ sst, const float* __restrict__ Wb,
    const float* __restrict__ dinvb,
    unsigned short* __restrict__ HwOut, unsigned short* __restrict__ HbOut)
{
  constexpr int NGB = (LEVEL == 1) ? 8 : 26;
  constexpr int OSTRIDEB = (LEVEL == 1) ? 32 : 104;
  constexpr int NG = 8 + NGB;
  __shared__ float WwL[30*32];
  __shared__ float WbL[30*OSTRIDEB];
  __shared__ float awL[60], abL[60];
  int t = threadIdx.x;
  if (t < 60) {
    int c = t % 30;
    bool isW = t < 30;
    const float4* p = (const float4*)((isW ? bktW : bktB) + c*128);
    float s1 = 0.f, s2 = 0.f;
#pragma unroll
    for (int k = 0; k < 32; ++k) { float4 v = p[k]; s1 += v.x + v.z; s2 += v.y + v.w; }
    float mean = s1/16384.f, var = s2/16384.f - mean*mean, inv = rsqrtf(var + 1e-5f);
    float aa = (isW ? gW : gB)[c]*inv;
    float* dst = isW ? awL : abL;
    dst[c] = aa; dst[30+c] = (isW ? beW : beB)[c] - mean*aa;
  }
  for (int idx = t; idx < 30*32; idx += 256) {
    int k = idx >> 5, c = idx & 31;
    WwL[idx] = (c < 30) ? Ww[k*30 + c] : 0.f;
  }
  if (LEVEL == 1) {
    for (int idx = t; idx < 30*32; idx += 256) {
      int k = idx >> 5, c = idx & 31;
      WbL[idx] = (c < 30) ? Wb[k*30 + c] : 0.f;
    }
  } else {
    for (int idx = t; idx < 30*OSTRIDEB; idx += 256) {
      int k = idx / OSTRIDEB, j = idx % OSTRIDEB;
      WbL[idx] = (j < 100) ? Wb[k*100 + j] : 0.f;
    }
  }
  __syncthreads();
  int gid = blockIdx.x * 256 + t;
  int row = gid / NG, g = gid % NG;
  if (g < 8) {
    const float4* Z4 = (const float4*)Zw + (size_t)row*8;
    float4 z4[8];
#pragma unroll
    for (int u = 0; u < 8; ++u) z4[u] = Z4[u];
    const float* z = (const float*)z4;
    float4 xv;
    int ch = 4*g;
    xv.x = (ch+0 < 30) ? awL[ch+0]*z[ch+0] + awL[30+ch+0] : 0.f;
    xv.y = (ch+1 < 30) ? awL[ch+1]*z[ch+1] + awL[30+ch+1] : 0.f;
    xv.z = (ch+2 < 30) ? awL[ch+2]*z[ch+2] + awL[30+ch+2] : 0.f;
    xv.w = (ch+3 < 30) ? awL[ch+3]*z[ch+3] + awL[30+ch+3] : 0.f;
    ((float4*)xst)[(size_t)row*8+g] = xv;
    float4 o = {0,0,0,0};
#pragma unroll
    for (int k = 0; k < 30; ++k) {
      float xk = awL[k]*z[k] + awL[30+k];
      float4 w = *(const float4*)(WwL + k*32 + 4*g);
      FMA4(o, xk, w);
    }
    float d = dinvw[row];
    us4 pv = { f2h(d*o.x), f2h(d*o.y), f2h(d*o.z), f2h(d*o.w) };
    unsigned short* dst = (LEVEL == 1) ? (HwOut + (size_t)row*64 + 4*g)
                                       : (HwOut + (size_t)row*32 + 4*g);
    *(us4*)dst = pv;
  } else {
    int gb = g - 8;
    const float4* Z4 = (const float4*)Zb + (size_t)row*8;
    float4 z4[8];
#pragma unroll
    for (int u = 0; u < 8; ++u) z4[u] = Z4[u];
    const float* z = (const float*)z4;
    if (gb < 8) {
      int ch = 4*gb;
      float4 sv;
      sv.x = (ch+0 < 30) ? abL[ch+0]*z[ch+0] + abL[30+ch+0] : 0.f;
      sv.y = (ch+1 < 30) ? abL[ch+1]*z[ch+1] + abL[30+ch+1] : 0.f;
      sv.z = (ch+2 < 30) ? abL[ch+2]*z[ch+2] + abL[30+ch+2] : 0.f;
      sv.w = (ch+3 < 30) ? abL[ch+3]*z[ch+3] + abL[30+ch+3] : 0.f;
      ((float4*)sst)[(size_t)row*8+gb] = sv;
    }
    float4 o = {0,0,0,0};
#pragma unroll
    for (int k = 0; k < 30; ++k) {
      float sk = abL[k]*z[k] + abL[30+k];
      float4 w = *(const float4*)(WbL + k*OSTRIDEB + 4*gb);
      FMA4(o, sk, w);
    }
    float d = dinvb[row];
    us4 pv = { f2h(d*o.x), f2h(d*o.y), f2h(d*o.z), f2h(d*o.w) };
    unsigned short* dst = (LEVEL == 1) ? (HbOut + (size_t)row*64 + 32 + 4*gb)
                                       : (HbOut + (size_t)row*104 + 4*gb);
    *(us4*)dst = pv;
  }
}

// fcpool with inline L3 finalize + fused softmax -> fp16 S [row][104]
__global__ __launch_bounds__(256) void k_fcpool(
    const float* __restrict__ Zw3, const float* __restrict__ bktW3,
    const float* __restrict__ gW3, const float* __restrict__ beW3,
    const float* __restrict__ Zb3, const float* __restrict__ bktB3,
    const float* __restrict__ g100, const float* __restrict__ be100,
    const float* __restrict__ s11, const float* __restrict__ s12,
    const float* __restrict__ Wfc, const float* __restrict__ bfc,
    float* __restrict__ x13, unsigned short* __restrict__ S)
{
  __shared__ float shm[14240];   // feat 64x160 = 10240 | Wl 40x100 = 4000
  __shared__ float aw3[60], ab3[200];
  float* feat = shm;
  float* Wl = shm + 10240;
  int t = threadIdx.x;
  int g0 = blockIdx.x * 64;
  if (t < 30) {
    const float4* p = (const float4*)(bktW3 + t*16);
    float s1 = 0.f, s2 = 0.f;
#pragma unroll
    for (int k = 0; k < 4; ++k) { float4 v = p[k]; s1 += v.x + v.z; s2 += v.y + v.w; }
    float mean = s1/16384.f, var = s2/16384.f - mean*mean, inv = rsqrtf(var + 1e-5f);
    float aa = gW3[t]*inv; aw3[t] = aa; aw3[30+t] = beW3[t] - mean*aa;
  } else if (t >= 64 && t < 164) {
    int c = t - 64;
    const float4* p = (const float4*)(bktB3 + c*16);
    float s1 = 0.f, s2 = 0.f;
#pragma unroll
    for (int k = 0; k < 4; ++k) { float4 v = p[k]; s1 += v.x + v.z; s2 += v.y + v.w; }
    float mean = s1/16384.f, var = s2/16384.f - mean*mean, inv = rsqrtf(var + 1e-5f);
    float aa = g100[c]*inv; ab3[c] = aa; ab3[100+c] = be100[c] - mean*aa;
  }
  __syncthreads();
  for (int idx = t; idx < 64*160; idx += 256) {
    int l = idx / 160, c = idx % 160;
    int g = g0 + l;
    float v;
    if (c < 30) v = s11[(size_t)g*32 + c];
    else if (c < 60) v = s12[(size_t)g*32 + (c-30)];
    else { int k = c - 60; v = ab3[k]*Zb3[(size_t)g*104 + k] + ab3[100 + k]; }
    feat[l*160 + c] = v;
  }
  for (int idx = t; idx < 64*32; idx += 256) {
    int l = idx >> 5, c = idx & 31;
    int g = g0 + l;
    x13[(size_t)g*32+c] = (c < 30) ? aw3[c]*Zw3[(size_t)g*32+c] + aw3[30+c] : 0.f;
  }
  int np = t >> 3, kg = t & 7;
  int n0 = np*2, n1 = np*2 + 1;
  int kbase = kg*12 + (kg < 4 ? kg : 4);
  int klen  = kg < 4 ? 13 : 12;
  float a0[13], a1[13];
#pragma unroll
  for (int j = 0; j < 13; ++j) { a0[j] = 0.f; a1[j] = 0.f; }
  for (int ch = 0; ch < 4; ++ch) {
    __syncthreads();
    for (int idx = t; idx < 4000; idx += 256) {
      int r = idx/100, j = idx%100;
      Wl[r*100 + j] = Wfc[(ch*40 + r)*100 + j];
    }
    __syncthreads();
    for (int kk = 0; kk < 40; ++kk) {
      float f0 = feat[n0*160 + ch*40+kk];
      float f1 = feat[n1*160 + ch*40+kk];
#pragma unroll
      for (int j = 0; j < 13; ++j) {
        if (j < klen) {
          float w = Wl[kk*100 + kbase + j];
          a0[j] += f0*w; a1[j] += f1*w;
        }
      }
    }
  }
  __syncthreads();
  float* sRow = shm;  // reuse as [64][100]
  for (int j = 0; j < klen; ++j) {
    int k = kbase + j;
    sRow[n0*100 + k] = a0[j] + bfc[k];
    sRow[n1*100 + k] = a1[j] + bfc[k];
  }
  __syncthreads();
  int n = t >> 2, part = t & 3;
  int i0 = part*25;
  float m = -3.4e38f;
  for (int i = 0; i < 25; ++i) m = fmaxf(m, sRow[n*100 + i0 + i]);
  m = fmaxf(m, __shfl_xor(m, 1));
  m = fmaxf(m, __shfl_xor(m, 2));
  float ev[25]; float s = 0.f;
  for (int i = 0; i < 25; ++i) { float e = __expf(sRow[n*100 + i0 + i] - m); ev[i] = e; s += e; }
  s += __shfl_xor(s, 1);
  s += __shfl_xor(s, 2);
  float rinv = 1.f / s;
  for (int i = 0; i < 25; ++i) S[(size_t)(g0+n)*104 + i0 + i] = f2h(ev[i] * rinv);
  if (part == 3) {
    S[(size_t)(g0+n)*104 + 100] = 0; S[(size_t)(g0+n)*104 + 101] = 0;
    S[(size_t)(g0+n)*104 + 102] = 0; S[(size_t)(g0+n)*104 + 103] = 0;
  }
}

// As = adj @ S (weighted): fp16 S [row][104], 13 lanes/row.
__global__ __launch_bounds__(256) void k_spmm_as(
    const unsigned short* __restrict__ S, const float* __restrict__ ellv,
    const unsigned short* __restrict__ ellc, const int* __restrict__ rowlen,
    float* __restrict__ Z)
{
  int t = threadIdx.x;
  int gid = blockIdx.x * 256 + t;
  int row = gid / 13, q = gid - row*13;
  int len = rowlen[row];
  const float4* ev = (const float4*)(ellv + (size_t)row * CAP);
  const uint2*  ec = (const uint2*) (ellc + (size_t)row * CAP);
  const uint4* HP = (const uint4*)(S + (size_t)(row >> 11) * ((size_t)NN*104));
  float acc[8] = {0,0,0,0,0,0,0,0};
  int nit = len >> 2;
  for (int i = 0; i < nit; ++i) {
    float4 v = ev[i];
    uint2 cc = ec[i];
    int c0 = cc.x & 0xffff, c1 = cc.x >> 16, c2 = cc.y & 0xffff, c3 = cc.y >> 16;
    uint4 g0 = HP[c0*13+q], g1 = HP[c1*13+q], g2 = HP[c2*13+q], g3 = HP[c3*13+q];
    ACC8(g0, v.x); ACC8(g1, v.y); ACC8(g2, v.z); ACC8(g3, v.w);
  }
  float* Zp = Z + (size_t)row*104 + q*8;
  float4 o0 = {acc[0],acc[1],acc[2],acc[3]}, o1 = {acc[4],acc[5],acc[6],acc[7]};
  ((float4*)Zp)[0] = o0; ((float4*)Zp)[1] = o1;
}

// TAIL: cooperative 64-block kernel = pool_part (+stage-1 max) -> 64-blk barrier ->
// stage-2 on blocks 0..7.
// R13: phase A fully vectorized — uint4/float4 staging, 4kx16d register tiles
// (5 ds_read_b128 per 64 FMA, was 17 scalar reads per 52); pool-reduce float4.
__global__ __launch_bounds__(256) void k_tail(
    const unsigned short* __restrict__ S, const float* __restrict__ x13,
    const float* __restrict__ As, const float* __restrict__ x11,
    const float* __restrict__ x12, float* __restrict__ pp, float* __restrict__ pm,
    const float* __restrict__ Wm, const float* __restrict__ g30s,
    const float* __restrict__ be30s, float* __restrict__ bktS2,
    int* __restrict__ cnt,
    const float* __restrict__ W1, const float* __restrict__ b1,
    const float* __restrict__ W2, const float* __restrict__ b2,
    float* __restrict__ out)
{
  __shared__ float shm[17664];   // 70.6 KB
  int blk = blockIdx.x, t = threadIdx.x;
  int* cntA = cnt;      // 64-block barrier
  int* cntB = cnt + 1;  // s2 8-block barriers
  // ---- phase A: pooled partials (vectorized) + stage-1 col max ----
  {
    float* sL = shm;            // [64][104] = 6656 (fp32 S)
    float* xA = shm + 6656;     // [64][32]  = 2048 (x13 incl. zero pad)
    float* xB = shm + 8704;     // [64][112] = 7168 (As 104 + zero pad)
    float* red = shm + 15872;   // [256]
    int b = blk >> 3, chunk = blk & 7;
    int g00 = b * 2048 + chunk * 256;
    // tile mapping: segment A (x13 cols): 50 threads = 25kt x 2dt(16) over d 0..31
    //               segment B (As cols): 175 threads = 25kt x 7dt(16) over d 0..111
    bool act = (t < 225);
    bool segA = (t < 50);
    int kt = 0, d0 = 0;
    if (segA) { kt = t >> 1; d0 = (t & 1) * 16; }
    else if (act) { int u = t - 50; kt = u / 7; d0 = (u % 7) * 16; }
    int k0 = kt * 4;
    float acc[4][16];
#pragma unroll
    for (int a = 0; a < 4; ++a)
#pragma unroll
      for (int j = 0; j < 16; ++j) acc[a][j] = 0.f;
    for (int tile = 0; tile < 4; ++tile) {
      int g0 = g00 + tile*64;
      __syncthreads();
      // stage sL: 64 rows x 13 uint4 (8 fp16 each)
      for (int idx = t; idx < 832; idx += 256) {
        int l = idx / 13, g = idx % 13;
        uint4 u4 = ((const uint4*)(S + (size_t)(g0+l)*104))[g];
        float2 f0 = h2f2(u4.x), f1 = h2f2(u4.y), f2 = h2f2(u4.z), f3 = h2f2(u4.w);
        float4 lo = {f0.x, f0.y, f1.x, f1.y};
        float4 hi = {f2.x, f2.y, f3.x, f3.y};
        *(float4*)&sL[l*104 + g*8]     = lo;
        *(float4*)&sL[l*104 + g*8 + 4] = hi;
      }
      // stage xA: 64 rows x 8 float4 (x13 stride 32, zero-padded cols 30..31)
      for (int idx = t; idx < 512; idx += 256) {
        int l = idx >> 3, g = idx & 7;
        *(float4*)&xA[l*32 + g*4] = ((const float4*)(x13 + (size_t)(g0+l)*32))[g];
      }
      // stage xB: 64 rows x 28 float4 (As 26 + 2 zero pad)
      for (int idx = t; idx < 64*28; idx += 256) {
        int l = idx / 28, g = idx % 28;
        float4 v;
        if (g < 26) v = ((const float4*)(As + (size_t)(g0+l)*104))[g];
        else { v.x = 0.f; v.y = 0.f; v.z = 0.f; v.w = 0.f; }
        *(float4*)&xB[l*112 + g*4] = v;
      }
      __syncthreads();
      if (act) {
        for (int kk = 0; kk < 64; ++kk) {
          float4 sv = *(const float4*)&sL[kk*104 + k0];
          float sc[4] = {sv.x, sv.y, sv.z, sv.w};
          const float* xp = segA ? &xA[kk*32 + d0] : &xB[kk*112 + d0];
          float4 xq0 = ((const float4*)xp)[0];
          float4 xq1 = ((const float4*)xp)[1];
          float4 xq2 = ((const float4*)xp)[2];
          float4 xq3 = ((const float4*)xp)[3];
          float xv[16] = {xq0.x,xq0.y,xq0.z,xq0.w, xq1.x,xq1.y,xq1.z,xq1.w,
                          xq2.x,xq2.y,xq2.z,xq2.w, xq3.x,xq3.y,xq3.z,xq3.w};
#pragma unroll
          for (int a = 0; a < 4; ++a)
#pragma unroll
            for (int j = 0; j < 16; ++j) acc[a][j] += sc[a]*xv[j];
        }
      }
    }
    if (act) {
      float* dst = pp + (size_t)blk * 13000;
      if (segA) {
        for (int a = 0; a < 4; ++a)
          for (int j = 0; j < 16; ++j) {
            int d = d0 + j;
            if (d < 30) dst[(k0+a)*130 + d] = acc[a][j];
          }
      } else {
        for (int a = 0; a < 4; ++a)
          for (int j = 0; j < 16; ++j) {
            int dd = d0 + j;
            if (dd < 100) dst[(k0+a)*130 + 30 + dd] = acc[a][j];
          }
      }
    }
    __syncthreads();
    {
      int c = t & 31, rg = t >> 5;
      const float* srcs[3] = {x11, x12, x13};
      for (int a = 0; a < 3; ++a) {
        const float* p = srcs[a] + (size_t)(g00+rg)*32 + c;
        float m = -3.4e38f;
        for (int it = 0; it < 32; ++it) m = fmaxf(m, p[it*256]);
        red[t] = m;
        __syncthreads();
        if (t < 30) {
          float mm = red[t];
          for (int g = 1; g < 8; ++g) mm = fmaxf(mm, red[g*32+t]);
          pm[(size_t)blk*90 + a*30 + t] = mm;
        }
        __syncthreads();
      }
    }
  }
  // ---- 64-block barrier ----
  __syncthreads();
  if (t == 0) {
    __threadfence();
    atomicAdd(cntA, 1);
    while (atomicAdd(cntA, 0) < 64) {}
    __threadfence();
  }
  __syncthreads();
  if (blk >= 8) return;
  // ---- phase B: stage 2 (register-tiled, fp32 A2 in LDS) ----
  {
    float* A2f  = shm;            // 10000
    float* buf1 = shm + 10000;    // 3000
    float* buf2 = shm + 13000;    // 3200 (T padded [100][32])
    float* WL   = shm + 16200;    // 960
    float* dl   = shm + 17160;    // 100
    float* st1  = shm + 17260;    // 30
    float* st2  = shm + 17290;    // 30
    float* coef = shm + 17320;    // 60
    float* x1L  = shm + 17380;    // 90
    float* x2L  = shm + 17470;    // 90
    float* hh   = shm + 17560;    // 50
    int b = blk;
    __syncthreads();
    // pool-reduce (float4-vectorized; per-element ch order unchanged)
    {
      const float4* pp4 = (const float4*)pp;
      for (int idx4 = t; idx4 < 3250; idx4 += 256) {
        float4 s = {0.f, 0.f, 0.f, 0.f};
        for (int ch = 0; ch < 8; ++ch) {
          float4 v = pp4[(size_t)(b*8 + ch)*3250 + idx4];
          s.x += v.x; s.y += v.y; s.z += v.z; s.w += v.w;
        }
        float sv[4] = {s.x, s.y, s.z, s.w};
        for (int j = 0; j < 4; ++j) {
          int gi = idx4*4 + j;
          int k = gi/130, d = gi%130;
          if (d < 30) buf1[k*30 + d] = sv[j];
          else A2f[k*100 + (d-30)] = sv[j];
        }
      }
    }
    __syncthreads();
    if (t < 100 && A2f[t*101] == 0.f) A2f[t*101] = 1.f;
    __syncthreads();
    if (t < 100) {
      float s = 0.f;
      for (int j = 0; j < 100; ++j) s += A2f[t*100 + j];
      dl[t] = s > 0.f ? rsqrtf(s) : 0.f;
    }
    __syncthreads();
    for (int idx = t; idx < 10000; idx += 256) {
      int i = idx/100, j = idx%100;
      A2f[idx] = dl[i]*dl[j]*A2f[idx];
    }
    int rp = t >> 2, cg = t & 3;
    int i0 = rp*2, c0 = cg*8;
    bool act = (t < 200);
    for (int L = 0; L < 3; ++L) {
      if (t < 30) { st1[t] = 0.f; st2[t] = 0.f; }
      const float* W = Wm + L*900;
      for (int idx = t; idx < 960; idx += 256) {
        int k = idx >> 5, c = idx & 31;
        WL[idx] = (c < 30) ? W[k*30 + c] : 0.f;
      }
      __syncthreads();
      if (act) {
        float a0[8] = {0,0,0,0,0,0,0,0}, a1[8] = {0,0,0,0,0,0,0,0};
        for (int k = 0; k < 30; ++k) {
          float xx0 = buf1[i0*30 + k], xx1 = buf1[(i0+1)*30 + k];
          float4 w0 = *(const float4*)&WL[k*32 + c0];
          float4 w1 = *(const float4*)&WL[k*32 + c0 + 4];
          a0[0] += xx0*w0.x; a0[1] += xx0*w0.y; a0[2] += xx0*w0.z; a0[3] += xx0*w0.w;
          a0[4] += xx0*w1.x; a0[5] += xx0*w1.y; a0[6] += xx0*w1.z; a0[7] += xx0*w1.w;
          a1[0] += xx1*w0.x; a1[1] += xx1*w0.y; a1[2] += xx1*w0.z; a1[3] += xx1*w0.w;
          a1[4] += xx1*w1.x; a1[5] += xx1*w1.y; a1[6] += xx1*w1.z; a1[7] += xx1*w1.w;
        }
        float4 s00 = {a0[0],a0[1],a0[2],a0[3]}, s01 = {a0[4],a0[5],a0[6],a0[7]};
        float4 s10 = {a1[0],a1[1],a1[2],a1[3]}, s11v = {a1[4],a1[5],a1[6],a1[7]};
        *(float4*)&buf2[i0*32 + c0]       = s00;
        *(float4*)&buf2[i0*32 + c0 + 4]   = s01;
        *(float4*)&buf2[(i0+1)*32 + c0]   = s10;
        *(float4*)&buf2[(i0+1)*32 + c0+4] = s11v;
      }
      __syncthreads();
      if (act) {
        float z0[8] = {0,0,0,0,0,0,0,0}, z1[8] = {0,0,0,0,0,0,0,0};
        for (int j = 0; j < 100; ++j) {
          float av0 = A2f[i0*100 + j], av1 = A2f[(i0+1)*100 + j];
          float4 t0 = *(const float4*)&buf2[j*32 + c0];
          float4 t1 = *(const float4*)&buf2[j*32 + c0 + 4];
          z0[0] += av0*t0.x; z0[1] += av0*t0.y; z0[2] += av0*t0.z; z0[3] += av0*t0.w;
          z0[4] += av0*t1.x; z0[5] += av0*t1.y; z0[6] += av0*t1.z; z0[7] += av0*t1.w;
          z1[0] += av1*t0.x; z1[1] += av1*t0.y; z1[2] += av1*t0.z; z1[3] += av1*t0.w;
          z1[4] += av1*t1.x; z1[5] += av1*t1.y; z1[6] += av1*t1.z; z1[7] += av1*t1.w;
        }
#pragma unroll
        for (int k = 0; k < 8; ++k) {
          int c = c0 + k;
          if (c < 30) {
            buf1[i0*30 + c]     = z0[k];
            buf1[(i0+1)*30 + c] = z1[k];
            atomicAdd(&st1[c], z0[k] + z1[k]);
            atomicAdd(&st2[c], z0[k]*z0[k] + z1[k]*z1[k]);
          }
        }
      }
      __syncthreads();
      if (t < 30) {
        atomicAdd(&bktS2[(L*30+t)*2],   st1[t]);
        atomicAdd(&bktS2[(L*30+t)*2+1], st2[t]);
      }
      __syncthreads();
      if (t == 0) {
        __threadfence();
        atomicAdd(cntB, 1);
        while (atomicAdd(cntB, 0) < (L+1)*8) {}
        __threadfence();
      }
      __syncthreads();
      if (t < 30) {
        float s1 = atomicAdd(&bktS2[(L*30+t)*2],   0.f);
        float s2 = atomicAdd(&bktS2[(L*30+t)*2+1], 0.f);
        float mean = s1/800.f, var = s2/800.f - mean*mean, inv = rsqrtf(var + 1e-5f);
        float aa = g30s[L*30+t]*inv;
        coef[t] = aa; coef[30+t] = be30s[L*30+t] - mean*aa;
      }
      __syncthreads();
      if (L < 2) {
        for (int idx = t; idx < 3000; idx += 256) {
          int c = idx % 30;
          buf1[idx] = coef[c]*buf1[idx] + coef[30+c];
        }
        __syncthreads();
        if (t < 30) {
          float m = -3.4e38f;
          for (int i = 0; i < 100; ++i) m = fmaxf(m, buf1[i*30+t]);
          x2L[L*30+t] = m;
        }
        __syncthreads();
      } else {
        if (t < 30) {
          float m = -3.4e38f;
          for (int i = 0; i < 100; ++i) m = fmaxf(m, coef[t]*buf1[i*30+t] + coef[30+t]);
          x2L[60+t] = m;
        }
      }
    }
    if (t < 90) {
      float m = -3.4e38f;
      for (int s = 0; s < 8; ++s) m = fmaxf(m, pm[(size_t)(b*8+s)*90 + t]);
      x1L[t] = m;
    }
    __syncthreads();
    if (t < 50) {
      float a = b1[t];
      for (int k = 0; k < 90; ++k) a += x1L[k]*W1[k*50+t];
      for (int k = 0; k < 90; ++k) a += x2L[k]*W1[(90+k)*50+t];
      hh[t] = fmaxf(a, 0.f);
    }
    __syncthreads();
    if (t < 6) {
      float a = b2[t];
      for (int j = 0; j < 50; ++j) a += hh[j]*W2[j*6+t];
      out[b*6+t] = a;
    }
  }
}

// ---------------- launcher ----------------
extern "C" void kernel_launch(void* const* d_in, const int* in_sizes, int n_in,
                              void* d_out, int out_size, void* d_ws, size_t ws_size,
                              hipStream_t stream)
{
  const float* x    = (const float*)d_in[0];
  const float* adj  = (const float*)d_in[1];
  const float* Win  = (const float*)d_in[2];
  const float* W3030= (const float*)d_in[3];
  const float* Wp13 = (const float*)d_in[4];
  // d_in[5]=b30, d_in[6]=b100: cancel through training-mode BN -> unused
  const float* Wfc  = (const float*)d_in[7];
  const float* bfc  = (const float*)d_in[8];
  const float* W1   = (const float*)d_in[9];
  const float* b1   = (const float*)d_in[10];
  const float* W2   = (const float*)d_in[11];
  const float* b2   = (const float*)d_in[12];
  const float* g30  = (const float*)d_in[13];
  const float* be30 = (const float*)d_in[14];
  const float* g100 = (const float*)d_in[15];
  const float* be100= (const float*)d_in[16];
  float* out = (float*)d_out;

  float* wsf = (float*)d_ws;
  float* bL1W = wsf + OF_B1W;  float* bL1B = wsf + OF_B1B;
  float* bL2W = wsf + OF_B2W;  float* bL2B = wsf + OF_B2B;
  float* bL3W = wsf + OF_B3W;  float* bL3B = wsf + OF_B3B;
  float* bktS2 = wsf + OF_S2;
  int*   cnt  = (int*)(wsf + OF_CNT);
  float* ellv  = wsf + OF_ELLV;
  unsigned short* ellc = (unsigned short*)(wsf + OF_ELLC);
  int*   rowlen = (int*)(wsf + OF_ROWLEN);
  float* dinvw = wsf + OF_DINVW;
  float* dinvb = wsf + OF_DINVB;
  unsigned short* Hwb   = (unsigned short*)(wsf + OF_HWB);
  unsigned short* Hw3   = (unsigned short*)(wsf + OF_HW3);
  unsigned short* Hb100 = (unsigned short*)(wsf + OF_HB100);
  unsigned short* S     = Hb100;   // S reuses HB100 (dead after L3-b spmm)
  float* Zw = wsf + OF_ZW;
  float* Zb = wsf + OF_ZB;         // stride 104; later reused as As
  float* x11 = wsf + OF_X11;
  float* x12 = wsf + OF_X12;
  float* x13 = wsf + OF_X13;
  float* s11 = wsf + OF_S11;
  float* s12 = wsf + OF_S12;
  float* pp  = wsf + OF_S11;       // pool partials reuse s11+s12 (dead after fcpool)
  float* partmax = wsf + OF_PARTMAX;

  // 9 dispatches
  k_build_ell<<<RTOT, 256, 0, stream>>>(adj, x, Win, ellv, ellc, rowlen, dinvw, dinvb, Hwb, wsf);

  k_spmm_pair<<<512, 256, 0, stream>>>(Hwb, ellv, ellc, rowlen, dinvw, dinvb, Zw, Zb, bL1W, bL1B);
  k_apply_gemm<1><<<1024, 256, 0, stream>>>(Zw, bL1W, g30+0, be30+0, x11, W3030+0, dinvw,
                                            Zb, bL1B, g30+90, be30+90, s11, W3030+2*900, dinvb, Hwb, Hwb);

  k_spmm_pair<<<512, 256, 0, stream>>>(Hwb, ellv, ellc, rowlen, dinvw, dinvb, Zw, Zb, bL2W, bL2B);
  k_apply_gemm<2><<<2176, 256, 0, stream>>>(Zw, bL2W, g30+30, be30+30, x12, W3030+900, dinvw,
                                            Zb, bL2B, g30+120, be30+120, s12, Wp13, dinvb, Hw3, Hb100);

  k_spmm_l3<<<1088, 256, 0, stream>>>(Hw3, Hb100, ellv, ellc, rowlen, dinvw, dinvb, Zw, Zb, bL3W, bL3B);
  k_fcpool<<<256, 256, 0, stream>>>(Zw, bL3W, g30+60, be30+60, Zb, bL3B, g100, be100,
                                    s11, s12, Wfc, bfc, x13, S);

  k_spmm_as<<<832, 256, 0, stream>>>(S, ellv, ellc, rowlen, Zb /* As */);
  k_tail<<<64, 256, 0, stream>>>(S, x13, Zb, x11, x12, pp, partmax,
                                 W3030+3*900, g30+150, be30+150, bktS2, cnt,
                                 W1, b1, W2, b2, out);
}